// Round 1
// baseline (190.085 us; speedup 1.0000x reference)
//
#include <hip/hip_runtime.h>

#define HDIM 512
#define BM 64
#define BK 64

typedef __attribute__((ext_vector_type(8))) short bf16x8;
typedef __attribute__((ext_vector_type(4))) float f32x4;

__device__ __forceinline__ unsigned short f2bf(float f){
  union { float f; unsigned int u; } c; c.f = f;
  unsigned int u = c.u;
  unsigned int r = u + 0x7fffu + ((u >> 16) & 1u);
  return (unsigned short)(r >> 16);
}
__device__ __forceinline__ float bf2f(unsigned short b){
  union { unsigned int u; float f; } c; c.u = ((unsigned int)b) << 16;
  return c.f;
}

// ---------------- kernel 1: convert Wrh (512x512 f32) -> bf16 ----------------
__global__ __launch_bounds__(256) void cvt_wrh(const float* __restrict__ W,
                                               unsigned short* __restrict__ out){
  int i = (blockIdx.x * 256 + threadIdx.x) * 4;   // grid 256 -> 262144 elems
  float4 f = *(const float4*)(W + i);
  out[i+0] = f2bf(f.x); out[i+1] = f2bf(f.y);
  out[i+2] = f2bf(f.z); out[i+3] = f2bf(f.w);
}

// ---------------- generic matvec: out[h] = dot(W[h][0..L-1], v) --------------
// grid 64 blocks x 256 thr, 8 rows/block (512 rows total)
__global__ __launch_bounds__(256) void matvec_k(const float* __restrict__ W,
    const float* __restrict__ v, float* __restrict__ out, int L){
  __shared__ float vl[1024];
  __shared__ float red[4];
  for (int i = threadIdx.x; i < L; i += 256) vl[i] = v[i];
  __syncthreads();
  int lane = threadIdx.x & 63, wid = threadIdx.x >> 6;
  for (int j = 0; j < 8; j++){
    int h = blockIdx.x * 8 + j;
    const float* Wr = W + (size_t)h * L;
    float a = 0.f;
    for (int k = threadIdx.x; k < L; k += 256) a += vl[k] * Wr[k];
    #pragma unroll
    for (int m = 1; m < 64; m <<= 1) a += __shfl_xor(a, m, 64);
    if (lane == 0) red[wid] = a;
    __syncthreads();
    if (threadIdx.x == 0) out[h] = red[0] + red[1] + red[2] + red[3];
    __syncthreads();
  }
}

// ---------------- kernel 3: fused GEMM + LN + sigmoid + partial sums ---------
// per WG: rows r0..r0+63, all 512 cols. 8 waves, each 64x64 output.
__global__ __launch_bounds__(512, 2) void fused_r(
    const float* __restrict__ hiddens,
    const unsigned short* __restrict__ wrhb,
    const float* __restrict__ xWri,
    const float* __restrict__ gr, const float* __restrict__ br,
    float* __restrict__ psum_rh, float* __restrict__ psum_h)
{
  __shared__ short As[BM * BK];        // 8 KB, XOR-swizzled
  __shared__ short Bs[HDIM * BK];      // 64 KB, XOR-swizzled; reused as r_lds
  __shared__ float redS[8 * 64];
  __shared__ float redQ[8 * 64];
  __shared__ float mu_s[64], rs_s[64];

  const int tid  = threadIdx.x;
  const int lane = tid & 63;
  const int wid  = tid >> 6;        // 0..7
  const int llo  = lane & 15;
  const int lhi  = lane >> 4;
  const int wcol = wid * 64;
  const int r0   = blockIdx.x * BM;

  f32x4 acc[4][4];
  #pragma unroll
  for (int i = 0; i < 4; i++)
    #pragma unroll
    for (int j = 0; j < 4; j++)
      #pragma unroll
      for (int k = 0; k < 4; k++) acc[i][j][k] = 0.f;

  const int arow  = tid >> 3;       // 0..63
  const int aslot = tid & 7;
  const float* aptr = hiddens + (size_t)(r0 + arow) * HDIM + aslot * 8;

  for (int kb = 0; kb < HDIM / BK; kb++){
    __syncthreads();
    // stage A (fp32 -> bf16, swizzled)
    {
      float4 f0 = *(const float4*)(aptr + kb * BK);
      float4 f1 = *(const float4*)(aptr + kb * BK + 4);
      bf16x8 v;
      v[0]=(short)f2bf(f0.x); v[1]=(short)f2bf(f0.y); v[2]=(short)f2bf(f0.z); v[3]=(short)f2bf(f0.w);
      v[4]=(short)f2bf(f1.x); v[5]=(short)f2bf(f1.y); v[6]=(short)f2bf(f1.z); v[7]=(short)f2bf(f1.w);
      *(bf16x8*)&As[arow * BK + ((aslot ^ (arow & 7)) << 3)] = v;
    }
    // stage B (bf16, swizzled): 512x64 tile of Wrh
    #pragma unroll
    for (int p = 0; p < 8; p++){
      int e = p * 512 + tid;
      int brow = e >> 3, bslot = e & 7;
      bf16x8 v = *(const bf16x8*)(wrhb + (size_t)brow * HDIM + kb * BK + bslot * 8);
      *(bf16x8*)&Bs[brow * BK + ((bslot ^ (brow & 7)) << 3)] = v;
    }
    __syncthreads();
    #pragma unroll
    for (int kk = 0; kk < 2; kk++){
      bf16x8 af[4], bfr[4];
      #pragma unroll
      for (int mi = 0; mi < 4; mi++){
        int row = mi * 16 + llo;
        int slot = kk * 4 + lhi;
        af[mi] = *(const bf16x8*)&As[row * BK + ((slot ^ (row & 7)) << 3)];
      }
      #pragma unroll
      for (int ni = 0; ni < 4; ni++){
        int row = wcol + ni * 16 + llo;
        int slot = kk * 4 + lhi;
        bfr[ni] = *(const bf16x8*)&Bs[row * BK + ((slot ^ (row & 7)) << 3)];
      }
      #pragma unroll
      for (int mi = 0; mi < 4; mi++)
        #pragma unroll
        for (int ni = 0; ni < 4; ni++)
          acc[mi][ni] = __builtin_amdgcn_mfma_f32_16x16x32_bf16(af[mi], bfr[ni], acc[mi][ni], 0, 0, 0);
    }
  }

  __syncthreads();   // all MFMA done; LDS reusable

  // add xWri, per-row stats (sum, sumsq over 512 cols)
  float xw[4], g4[4], b4[4];
  #pragma unroll
  for (int ni = 0; ni < 4; ni++){
    int c = wcol + ni * 16 + llo;
    xw[ni] = xWri[c];
    g4[ni] = gr[c];
    b4[ni] = br[c];
  }
  #pragma unroll
  for (int mi = 0; mi < 4; mi++){
    #pragma unroll
    for (int rr = 0; rr < 4; rr++){
      float sv = 0.f, qv = 0.f;
      #pragma unroll
      for (int ni = 0; ni < 4; ni++){
        float v = acc[mi][ni][rr] + xw[ni];
        acc[mi][ni][rr] = v;
        sv += v; qv += v * v;
      }
      #pragma unroll
      for (int m = 1; m < 16; m <<= 1){
        sv += __shfl_xor(sv, m, 64);
        qv += __shfl_xor(qv, m, 64);
      }
      if (llo == 0){
        int row = mi * 16 + lhi * 4 + rr;
        redS[wid * 64 + row] = sv;
        redQ[wid * 64 + row] = qv;
      }
    }
  }
  __syncthreads();
  if (tid < 64){
    float S = 0.f, Q = 0.f;
    #pragma unroll
    for (int w = 0; w < 8; w++){ S += redS[w * 64 + tid]; Q += redQ[w * 64 + tid]; }
    float mu  = S * (1.f / 512.f);
    float var = Q * (1.f / 512.f) - mu * mu;
    mu_s[tid] = mu;
    rs_s[tid] = rsqrtf(var + 1e-5f);
  }
  __syncthreads();

  // r = sigmoid(LN(v)) -> store bf16 into reused Bs as [64][512]
  unsigned short* rlds = (unsigned short*)Bs;
  #pragma unroll
  for (int mi = 0; mi < 4; mi++){
    #pragma unroll
    for (int rr = 0; rr < 4; rr++){
      int row = mi * 16 + lhi * 4 + rr;
      float mu = mu_s[row], rs = rs_s[row];
      #pragma unroll
      for (int ni = 0; ni < 4; ni++){
        float v = (acc[mi][ni][rr] - mu) * rs * g4[ni] + b4[ni];
        float r = 1.f / (1.f + expf(-v));
        rlds[row * HDIM + wcol + ni * 16 + llo] = f2bf(r);
      }
    }
  }
  __syncthreads();

  // coalesced column loop: partial sums over this WG's 64 rows
  float accR = 0.f, accH = 0.f;
  const float* hb = hiddens + (size_t)r0 * HDIM + tid;
  for (int row = 0; row < BM; row++){
    float hv = hb[(size_t)row * HDIM];
    float rv = bf2f(rlds[row * HDIM + tid]);
    accR += rv * hv;
    accH += hv;
  }
  psum_rh[(size_t)blockIdx.x * HDIM + tid] = accR;
  psum_h [(size_t)blockIdx.x * HDIM + tid] = accH;
}

// ---------------- kernel 4: reduce partials, build cat vectors ---------------
__global__ __launch_bounds__(256) void reduce_psums(
    const float* __restrict__ psum_rh, const float* __restrict__ psum_h,
    const float* __restrict__ x, float* __restrict__ catz, float* __restrict__ catu,
    int nblk)
{
  __shared__ float L[8][32];
  int b = blockIdx.x, t = threadIdx.x;
  if (b < 32){
    const float* P = (b < 16) ? psum_rh : psum_h;
    int c0 = (b & 15) * 32;
    int wj = t >> 5, ci = t & 31;
    float a = 0.f;
    for (int s = wj; s < nblk; s += 8) a += P[(size_t)s * 512 + c0 + ci];
    L[wj][ci] = a;
    __syncthreads();
    if (t < 32){
      float r = 0.f;
      #pragma unroll
      for (int w = 0; w < 8; w++) r += L[w][t];
      if (b < 16) catu[512 + c0 + t] = r;   // (r*hiddens).sum(0)
      else        catz[512 + c0 + t] = r;   // hidden_sum
    }
  } else {
    int i = ((b - 32) & 1) * 256 + t;       // 0..511
    if (b < 34) catz[i] = x[i];
    else        catu[i] = x[i];
  }
}

// ---------------- kernel 7: final LN + gates + output ------------------------
__global__ __launch_bounds__(512) void finalize_k(
    const float* __restrict__ zpre, const float* __restrict__ upre,
    const float* __restrict__ gz, const float* __restrict__ bz,
    const float* __restrict__ gu, const float* __restrict__ bu,
    const float* __restrict__ catz, float* __restrict__ out)
{
  __shared__ float R[8][4];
  int t = threadIdx.x, lane = t & 63, wid = t >> 6;
  float zp = zpre[t], up = upre[t];
  float zs = zp, zq = zp * zp, us = up, uq = up * up;
  #pragma unroll
  for (int m = 1; m < 64; m <<= 1){
    zs += __shfl_xor(zs, m, 64); zq += __shfl_xor(zq, m, 64);
    us += __shfl_xor(us, m, 64); uq += __shfl_xor(uq, m, 64);
  }
  if (lane == 0){ R[wid][0] = zs; R[wid][1] = zq; R[wid][2] = us; R[wid][3] = uq; }
  __syncthreads();
  float ZS = 0.f, ZQ = 0.f, US = 0.f, UQ = 0.f;
  #pragma unroll
  for (int w = 0; w < 8; w++){ ZS += R[w][0]; ZQ += R[w][1]; US += R[w][2]; UQ += R[w][3]; }
  float zmu = ZS / 512.f, zrs = rsqrtf(ZQ / 512.f - zmu * zmu + 1e-5f);
  float umu = US / 512.f, urs = rsqrtf(UQ / 512.f - umu * umu + 1e-5f);
  float z = 1.f / (1.f + expf(-((zp - zmu) * zrs * gz[t] + bz[t])));
  float u = tanhf((up - umu) * urs * gu[t] + bu[t]);
  float hs = catz[512 + t];
  out[t] = z * hs + (1.f - z) * u;
}

// -----------------------------------------------------------------------------
extern "C" void kernel_launch(void* const* d_in, const int* in_sizes, int n_in,
                              void* d_out, int out_size, void* d_ws, size_t ws_size,
                              hipStream_t stream)
{
  const float* x   = (const float*)d_in[0];
  const float* hid = (const float*)d_in[1];
  const float* Wz  = (const float*)d_in[2];
  const float* Wri = (const float*)d_in[3];
  const float* Wrh = (const float*)d_in[4];
  const float* Wu  = (const float*)d_in[5];
  const float* gz  = (const float*)d_in[6];
  const float* bz  = (const float*)d_in[7];
  const float* gr  = (const float*)d_in[8];
  const float* br  = (const float*)d_in[9];
  const float* gu  = (const float*)d_in[10];
  const float* bu  = (const float*)d_in[11];
  (void)n_in; (void)out_size; (void)ws_size;

  const int M    = in_sizes[1] / HDIM;   // 65536
  const int nblk = M / BM;               // 1024

  char* ws = (char*)d_ws;
  unsigned short* wrhb = (unsigned short*)ws;               // 512 KB
  float* xwri    = (float*)(ws + 524288);                   // 2 KB
  float* psum_rh = (float*)(ws + 526336);                   // nblk*512*4
  float* psum_h  = (float*)(ws + 526336 + (size_t)nblk * 2048);
  char*  p2      = ws + 526336 + (size_t)nblk * 4096;
  float* catz    = (float*)p2;                              // 4 KB
  float* catu    = (float*)(p2 + 4096);                     // 4 KB
  float* zpre    = (float*)(p2 + 8192);                     // 2 KB
  float* upre    = (float*)(p2 + 10240);                    // 2 KB
  float* out     = (float*)d_out;

  hipLaunchKernelGGL(cvt_wrh,      dim3(256),  dim3(256), 0, stream, Wrh, wrhb);
  hipLaunchKernelGGL(matvec_k,     dim3(64),   dim3(256), 0, stream, Wri, x, xwri, 512);
  hipLaunchKernelGGL(fused_r,      dim3(nblk), dim3(512), 0, stream, hid, wrhb, xwri, gr, br, psum_rh, psum_h);
  hipLaunchKernelGGL(reduce_psums, dim3(36),   dim3(256), 0, stream, psum_rh, psum_h, x, catz, catu, nblk);
  hipLaunchKernelGGL(matvec_k,     dim3(64),   dim3(256), 0, stream, Wz, catz, zpre, 1024);
  hipLaunchKernelGGL(matvec_k,     dim3(64),   dim3(256), 0, stream, Wu, catu, upre, 1024);
  hipLaunchKernelGGL(finalize_k,   dim3(1),    dim3(512), 0, stream, zpre, upre, gz, bz, gu, bu, catz, out);
}

// Round 3
// 141.746 us; speedup vs baseline: 1.3410x; 1.3410x over previous
//
#include <hip/hip_runtime.h>

#define HDIM 512
#define BM 64

typedef __attribute__((ext_vector_type(8))) short bf16x8;
typedef __attribute__((ext_vector_type(4))) float f32x4;

__device__ __forceinline__ unsigned short f2bf(float f){
  union { float f; unsigned int u; } c; c.f = f;
  unsigned int u = c.u;
  unsigned int r = u + 0x7fffu + ((u >> 16) & 1u);
  return (unsigned short)(r >> 16);
}
__device__ __forceinline__ float bf2f(unsigned short b){
  union { unsigned int u; float f; } c; c.u = ((unsigned int)b) << 16;
  return c.f;
}

// ---------------- kernel 1: cvt Wrh -> bf16  +  xwri = Wri @ x ---------------
__global__ __launch_bounds__(256) void prep_k(const float* __restrict__ Wrh,
    unsigned short* __restrict__ wrhb, const float* __restrict__ Wri,
    const float* __restrict__ x, float* __restrict__ xwri)
{
  int b = blockIdx.x;
  if (b < 256){
    int i = (b * 256 + threadIdx.x) * 4;
    float4 f = *(const float4*)(Wrh + i);
    wrhb[i+0] = f2bf(f.x); wrhb[i+1] = f2bf(f.y);
    wrhb[i+2] = f2bf(f.z); wrhb[i+3] = f2bf(f.w);
  } else {
    int lane = threadIdx.x & 63, wid = threadIdx.x >> 6;
    int row = (b - 256) * 4 + wid;
    const float* Wr = Wri + (size_t)row * HDIM;
    float a = 0.f;
    #pragma unroll
    for (int k = 0; k < HDIM / 64; k++) a += x[k*64 + lane] * Wr[k*64 + lane];
    #pragma unroll
    for (int m = 1; m < 64; m <<= 1) a += __shfl_xor(a, m, 64);
    if (lane == 0) xwri[row] = a;
  }
}

// ---------------- kernel 2: fused GEMM + LN + sigmoid + partial sums ---------
// per WG: rows r0..r0+63, all 512 cols; 8 waves, wave wid owns cols wid*64..+63.
// A (hiddens tile) staged ONCE in LDS (bf16, XOR-swizzled); B (Wrh bf16) read
// directly from global (L2-resident, identical across WGs) -> barrier-free K loop.
__global__ __launch_bounds__(512, 4) void fused_r(
    const float* __restrict__ hiddens,
    const unsigned short* __restrict__ wrhb,
    const float* __restrict__ xWri,
    const float* __restrict__ gr, const float* __restrict__ br,
    float* __restrict__ psum_rh, float* __restrict__ psum_h)
{
  __shared__ short As[BM * HDIM];      // 64 KB, [row][col] bf16, byte^((row&7)<<4)
  __shared__ float redS[8 * 64];
  __shared__ float redQ[8 * 64];
  __shared__ float mu_s[64], rs_s[64];

  const int tid  = threadIdx.x;
  const int lane = tid & 63;
  const int wid  = tid >> 6;
  const int llo  = lane & 15;
  const int lhi  = lane >> 4;
  const int wcol = wid * 64;
  const int r0   = blockIdx.x * BM;

  // ---- stage whole A tile: thread -> row tid>>3, col chunks (tid&7)*8 + i*64
  {
    int arow = tid >> 3;
    int c0   = (tid & 7) * 8;
    const float* ap = hiddens + (size_t)(r0 + arow) * HDIM + c0;
    char* asb = (char*)As + arow * 1024;
    int sw = (arow & 7) << 4;
    #pragma unroll
    for (int i = 0; i < 8; i++){
      float4 f0 = *(const float4*)(ap + i * 64);
      float4 f1 = *(const float4*)(ap + i * 64 + 4);
      bf16x8 v;
      v[0]=(short)f2bf(f0.x); v[1]=(short)f2bf(f0.y); v[2]=(short)f2bf(f0.z); v[3]=(short)f2bf(f0.w);
      v[4]=(short)f2bf(f1.x); v[5]=(short)f2bf(f1.y); v[6]=(short)f2bf(f1.z); v[7]=(short)f2bf(f1.w);
      *(bf16x8*)(asb + ((c0 * 2 + i * 128) ^ sw)) = v;
    }
  }
  __syncthreads();

  f32x4 acc[4][4];
  #pragma unroll
  for (int i = 0; i < 4; i++)
    #pragma unroll
    for (int j = 0; j < 4; j++)
      #pragma unroll
      for (int k = 0; k < 4; k++) acc[i][j][k] = 0.f;

  // ---- barrier-free K loop: A frags from LDS, B frags from global (L2)
  #pragma unroll 2
  for (int kb = 0; kb < 8; kb++){
    #pragma unroll
    for (int kk = 0; kk < 2; kk++){
      bf16x8 af[4], bfr[4];
      #pragma unroll
      for (int ni = 0; ni < 4; ni++)
        bfr[ni] = *(const bf16x8*)(wrhb + (size_t)(wcol + ni*16 + llo) * HDIM
                                   + kb*64 + kk*32 + lhi*8);
      #pragma unroll
      for (int mi = 0; mi < 4; mi++){
        int row = mi * 16 + llo;
        af[mi] = *(const bf16x8*)((char*)As + row * 1024
                   + ((kb*128 + kk*64 + lhi*16) ^ ((row & 7) << 4)));
      }
      #pragma unroll
      for (int mi = 0; mi < 4; mi++)
        #pragma unroll
        for (int ni = 0; ni < 4; ni++)
          acc[mi][ni] = __builtin_amdgcn_mfma_f32_16x16x32_bf16(af[mi], bfr[ni], acc[mi][ni], 0, 0, 0);
    }
  }

  // ---- add xWri, per-row LN stats
  float xw[4], g4[4], b4[4];
  #pragma unroll
  for (int ni = 0; ni < 4; ni++){
    int c = wcol + ni * 16 + llo;
    xw[ni] = xWri[c];
    g4[ni] = gr[c];
    b4[ni] = br[c];
  }
  #pragma unroll
  for (int mi = 0; mi < 4; mi++){
    #pragma unroll
    for (int rr = 0; rr < 4; rr++){
      float sv = 0.f, qv = 0.f;
      #pragma unroll
      for (int ni = 0; ni < 4; ni++){
        float v = acc[mi][ni][rr] + xw[ni];
        acc[mi][ni][rr] = v;
        sv += v; qv += v * v;
      }
      #pragma unroll
      for (int m = 1; m < 16; m <<= 1){
        sv += __shfl_xor(sv, m, 64);
        qv += __shfl_xor(qv, m, 64);
      }
      if (llo == 0){
        int row = mi * 16 + lhi * 4 + rr;
        redS[wid * 64 + row] = sv;
        redQ[wid * 64 + row] = qv;
      }
    }
  }
  __syncthreads();
  if (tid < 64){
    float S = 0.f, Q = 0.f;
    #pragma unroll
    for (int w = 0; w < 8; w++){ S += redS[w * 64 + tid]; Q += redQ[w * 64 + tid]; }
    float mu  = S * (1.f / 512.f);
    float var = Q * (1.f / 512.f) - mu * mu;
    mu_s[tid] = mu;
    rs_s[tid] = rsqrtf(var + 1e-5f);
  }
  __syncthreads();

  // ---- r = sigmoid(LN(v)); psums from h (bf16) in As; reduce over lhi
  float prh[4] = {0.f, 0.f, 0.f, 0.f};
  float ph [4] = {0.f, 0.f, 0.f, 0.f};
  #pragma unroll
  for (int mi = 0; mi < 4; mi++){
    #pragma unroll
    for (int rr = 0; rr < 4; rr++){
      int row = mi * 16 + lhi * 4 + rr;
      float mu = mu_s[row], rs = rs_s[row];
      int sw = (row & 7) << 4;
      #pragma unroll
      for (int ni = 0; ni < 4; ni++){
        float v = (acc[mi][ni][rr] - mu) * rs * g4[ni] + b4[ni];
        float r = 1.f / (1.f + expf(-v));
        int col = wcol + ni * 16 + llo;
        float h = bf2f(*(const unsigned short*)((char*)As + row * 1024 + ((col * 2) ^ sw)));
        prh[ni] += r * h;
        ph [ni] += h;
      }
    }
  }
  #pragma unroll
  for (int ni = 0; ni < 4; ni++){
    prh[ni] += __shfl_xor(prh[ni], 16, 64);
    prh[ni] += __shfl_xor(prh[ni], 32, 64);
    ph [ni] += __shfl_xor(ph [ni], 16, 64);
    ph [ni] += __shfl_xor(ph [ni], 32, 64);
  }
  if (lhi == 0){
    #pragma unroll
    for (int ni = 0; ni < 4; ni++){
      int col = wcol + ni * 16 + llo;
      psum_rh[(size_t)blockIdx.x * HDIM + col] = prh[ni];
      psum_h [(size_t)blockIdx.x * HDIM + col] = ph[ni];
    }
  }
}

// ---------------- kernel 3: reduce partials, build cat vectors ---------------
__global__ __launch_bounds__(256) void reduce_psums(
    const float* __restrict__ psum_rh, const float* __restrict__ psum_h,
    const float* __restrict__ x, float* __restrict__ catz, float* __restrict__ catu,
    int nblk)
{
  __shared__ float L[8][32];
  int b = blockIdx.x, t = threadIdx.x;
  if (b < 32){
    const float* P = (b < 16) ? psum_rh : psum_h;
    int c0 = (b & 15) * 32;
    int wj = t >> 5, ci = t & 31;
    float a = 0.f;
    for (int s = wj; s < nblk; s += 8) a += P[(size_t)s * 512 + c0 + ci];
    L[wj][ci] = a;
    __syncthreads();
    if (t < 32){
      float r = 0.f;
      #pragma unroll
      for (int w = 0; w < 8; w++) r += L[w][t];
      if (b < 16) catu[512 + c0 + t] = r;   // (r*hiddens).sum(0)
      else        catz[512 + c0 + t] = r;   // hidden_sum
    }
  } else {
    int i = ((b - 32) & 1) * 256 + t;       // 0..511
    if (b < 34) catz[i] = x[i];
    else        catu[i] = x[i];
  }
}

// ---------------- kernel 4: zpre = Wz@catz, upre = Wu@catu (one launch) ------
__global__ __launch_bounds__(256) void matvec_zu(
    const float* __restrict__ Wz, const float* __restrict__ Wu,
    const float* __restrict__ catz, const float* __restrict__ catu,
    float* __restrict__ zpre, float* __restrict__ upre)
{
  int b = blockIdx.x, lane = threadIdx.x & 63, wid = threadIdx.x >> 6;
  int row = (b & 127) * 4 + wid;
  const float* W = (b < 128) ? Wz : Wu;
  const float* v = (b < 128) ? catz : catu;
  float*       o = (b < 128) ? zpre : upre;
  const float* Wr = W + (size_t)row * 1024;
  float a = 0.f;
  #pragma unroll
  for (int k = 0; k < 1024 / 64; k++) a += v[k*64 + lane] * Wr[k*64 + lane];
  #pragma unroll
  for (int m = 1; m < 64; m <<= 1) a += __shfl_xor(a, m, 64);
  if (lane == 0) o[row] = a;
}

// ---------------- kernel 5: final LN + gates + output ------------------------
__global__ __launch_bounds__(512) void finalize_k(
    const float* __restrict__ zpre, const float* __restrict__ upre,
    const float* __restrict__ gz, const float* __restrict__ bz,
    const float* __restrict__ gu, const float* __restrict__ bu,
    const float* __restrict__ catz, float* __restrict__ out)
{
  __shared__ float R[8][4];
  int t = threadIdx.x, lane = t & 63, wid = t >> 6;
  float zp = zpre[t], up = upre[t];
  float zs = zp, zq = zp * zp, us = up, uq = up * up;
  #pragma unroll
  for (int m = 1; m < 64; m <<= 1){
    zs += __shfl_xor(zs, m, 64); zq += __shfl_xor(zq, m, 64);
    us += __shfl_xor(us, m, 64); uq += __shfl_xor(uq, m, 64);
  }
  if (lane == 0){ R[wid][0] = zs; R[wid][1] = zq; R[wid][2] = us; R[wid][3] = uq; }
  __syncthreads();
  float ZS = 0.f, ZQ = 0.f, US = 0.f, UQ = 0.f;
  #pragma unroll
  for (int w = 0; w < 8; w++){ ZS += R[w][0]; ZQ += R[w][1]; US += R[w][2]; UQ += R[w][3]; }
  float zmu = ZS / 512.f, zrs = rsqrtf(ZQ / 512.f - zmu * zmu + 1e-5f);
  float umu = US / 512.f, urs = rsqrtf(UQ / 512.f - umu * umu + 1e-5f);
  float z = 1.f / (1.f + expf(-((zp - zmu) * zrs * gz[t] + bz[t])));
  float u = tanhf((up - umu) * urs * gu[t] + bu[t]);
  float hs = catz[512 + t];
  out[t] = z * hs + (1.f - z) * u;
}

// -----------------------------------------------------------------------------
extern "C" void kernel_launch(void* const* d_in, const int* in_sizes, int n_in,
                              void* d_out, int out_size, void* d_ws, size_t ws_size,
                              hipStream_t stream)
{
  const float* x   = (const float*)d_in[0];
  const float* hid = (const float*)d_in[1];
  const float* Wz  = (const float*)d_in[2];
  const float* Wri = (const float*)d_in[3];
  const float* Wrh = (const float*)d_in[4];
  const float* Wu  = (const float*)d_in[5];
  const float* gz  = (const float*)d_in[6];
  const float* bz  = (const float*)d_in[7];
  const float* gr  = (const float*)d_in[8];
  const float* br  = (const float*)d_in[9];
  const float* gu  = (const float*)d_in[10];
  const float* bu  = (const float*)d_in[11];
  (void)n_in; (void)out_size; (void)ws_size;

  const int M    = in_sizes[1] / HDIM;   // 65536
  const int nblk = M / BM;               // 1024

  char* ws = (char*)d_ws;
  unsigned short* wrhb = (unsigned short*)ws;               // 512 KB
  float* xwri    = (float*)(ws + 524288);                   // 2 KB
  float* psum_rh = (float*)(ws + 526336);                   // nblk*512*4
  float* psum_h  = (float*)(ws + 526336 + (size_t)nblk * 2048);
  char*  p2      = ws + 526336 + (size_t)nblk * 4096;
  float* catz    = (float*)p2;                              // 4 KB
  float* catu    = (float*)(p2 + 4096);                     // 4 KB
  float* zpre    = (float*)(p2 + 8192);                     // 2 KB
  float* upre    = (float*)(p2 + 10240);                    // 2 KB
  float* out     = (float*)d_out;

  hipLaunchKernelGGL(prep_k,       dim3(384),  dim3(256), 0, stream, Wrh, wrhb, Wri, x, xwri);
  hipLaunchKernelGGL(fused_r,      dim3(nblk), dim3(512), 0, stream, hid, wrhb, xwri, gr, br, psum_rh, psum_h);
  hipLaunchKernelGGL(reduce_psums, dim3(36),   dim3(256), 0, stream, psum_rh, psum_h, x, catz, catu, nblk);
  hipLaunchKernelGGL(matvec_zu,    dim3(256),  dim3(256), 0, stream, Wz, Wu, catz, catu, zpre, upre);
  hipLaunchKernelGGL(finalize_k,   dim3(1),    dim3(512), 0, stream, zpre, upre, gz, bz, gu, bu, catz, out);
}

// Round 4
// 118.265 us; speedup vs baseline: 1.6073x; 1.1985x over previous
//
#include <hip/hip_runtime.h>

#define HDIM 512
#define BM 64

typedef __attribute__((ext_vector_type(8))) short bf16x8;
typedef __attribute__((ext_vector_type(4))) float f32x4;

__device__ __forceinline__ unsigned short f2bf(float f){
  union { float f; unsigned int u; } c; c.f = f;
  unsigned int u = c.u;
  unsigned int r = u + 0x7fffu + ((u >> 16) & 1u);
  return (unsigned short)(r >> 16);
}
__device__ __forceinline__ float bf2f(unsigned short b){
  union { unsigned int u; float f; } c; c.u = ((unsigned int)b) << 16;
  return c.f;
}

// ---------------- kernel 1: pack Wrh -> per-wave MFMA fragment order (bf16)
//                  + xwri = Wri @ x
// wpack layout (bf16x8 units): [g][lane], g = (wc*16 + kb*2+kk)*4 + ni,
// lane -> row = wc*64 + ni*16 + (lane&15), k0 = (kb*2+kk)*32 + (lane>>4)*8.
// In fused_r a wave reads wpack with wave-uniform base + lane*16B: coalesced.
__global__ __launch_bounds__(256) void prep_k(const float* __restrict__ Wrh,
    unsigned short* __restrict__ wpack, const float* __restrict__ Wri,
    const float* __restrict__ x, float* __restrict__ xwri)
{
  int b = blockIdx.x;
  if (b < 128){
    int t    = b * 256 + threadIdx.x;   // 0..32767
    int lane = t & 63;
    int g    = t >> 6;                  // 0..511
    int ni   = g & 3;
    int kkk  = (g >> 2) & 15;
    int wc   = g >> 6;
    int row  = wc * 64 + ni * 16 + (lane & 15);
    int k0   = kkk * 32 + (lane >> 4) * 8;
    const float* src = Wrh + (size_t)row * HDIM + k0;
    float4 f0 = *(const float4*)(src);
    float4 f1 = *(const float4*)(src + 4);
    bf16x8 v;
    v[0]=(short)f2bf(f0.x); v[1]=(short)f2bf(f0.y); v[2]=(short)f2bf(f0.z); v[3]=(short)f2bf(f0.w);
    v[4]=(short)f2bf(f1.x); v[5]=(short)f2bf(f1.y); v[6]=(short)f2bf(f1.z); v[7]=(short)f2bf(f1.w);
    *(bf16x8*)(wpack + (size_t)t * 8) = v;
  } else {
    int lane = threadIdx.x & 63, wid = threadIdx.x >> 6;
    int row = (b - 128) * 4 + wid;
    const float* Wr = Wri + (size_t)row * HDIM;
    float a = 0.f;
    #pragma unroll
    for (int k = 0; k < HDIM / 64; k++) a += x[k*64 + lane] * Wr[k*64 + lane];
    #pragma unroll
    for (int m = 1; m < 64; m <<= 1) a += __shfl_xor(a, m, 64);
    if (lane == 0) xwri[row] = a;
  }
}

// ---------------- kernel 2: fused GEMM + LN + sigmoid + partial sums ---------
// per WG: rows r0..r0+63, all 512 cols; 8 waves, wave wid owns cols wid*64..+63.
// A staged ONCE in LDS (bf16, XOR-swizzled). B read from wpack: wave-uniform
// base + lane*16 -> coalesced L2 hits. K loop is barrier-free.
__global__ __launch_bounds__(512, 4) void fused_r(
    const float* __restrict__ hiddens,
    const unsigned short* __restrict__ wpack,
    const float* __restrict__ xWri,
    const float* __restrict__ gr, const float* __restrict__ br,
    float* __restrict__ psum_rh, float* __restrict__ psum_h)
{
  __shared__ short As[BM * HDIM];      // 64 KB, [row][col] bf16, byte^((row&7)<<4)
  __shared__ float redS[8 * 64];
  __shared__ float redQ[8 * 64];
  __shared__ float mu_s[64], rs_s[64];

  const int tid  = threadIdx.x;
  const int lane = tid & 63;
  const int wid  = tid >> 6;
  const int llo  = lane & 15;
  const int lhi  = lane >> 4;
  const int wcol = wid * 64;
  const int r0   = blockIdx.x * BM;

  // ---- stage whole A tile: thread -> row tid>>3, col chunks (tid&7)*8 + i*64
  {
    int arow = tid >> 3;
    int c0   = (tid & 7) * 8;
    const float* ap = hiddens + (size_t)(r0 + arow) * HDIM + c0;
    char* asb = (char*)As + arow * 1024;
    int sw = (arow & 7) << 4;
    #pragma unroll
    for (int i = 0; i < 8; i++){
      float4 f0 = *(const float4*)(ap + i * 64);
      float4 f1 = *(const float4*)(ap + i * 64 + 4);
      bf16x8 v;
      v[0]=(short)f2bf(f0.x); v[1]=(short)f2bf(f0.y); v[2]=(short)f2bf(f0.z); v[3]=(short)f2bf(f0.w);
      v[4]=(short)f2bf(f1.x); v[5]=(short)f2bf(f1.y); v[6]=(short)f2bf(f1.z); v[7]=(short)f2bf(f1.w);
      *(bf16x8*)(asb + ((c0 * 2 + i * 128) ^ sw)) = v;
    }
  }
  __syncthreads();

  f32x4 acc[4][4];
  #pragma unroll
  for (int i = 0; i < 4; i++)
    #pragma unroll
    for (int j = 0; j < 4; j++)
      #pragma unroll
      for (int k = 0; k < 4; k++) acc[i][j][k] = 0.f;

  // ---- barrier-free K loop: A frags from LDS, B frags coalesced from wpack
  const bf16x8* wp = (const bf16x8*)wpack + ((size_t)wid * 16 * 4) * 64 + lane;
  #pragma unroll 2
  for (int kb = 0; kb < 8; kb++){
    #pragma unroll
    for (int kk = 0; kk < 2; kk++){
      const bf16x8* wpi = wp + (kb * 2 + kk) * 4 * 64;
      bf16x8 af[4], bfr[4];
      #pragma unroll
      for (int ni = 0; ni < 4; ni++)
        bfr[ni] = wpi[ni * 64];
      #pragma unroll
      for (int mi = 0; mi < 4; mi++){
        int row = mi * 16 + llo;
        af[mi] = *(const bf16x8*)((char*)As + row * 1024
                   + ((kb*128 + kk*64 + lhi*16) ^ ((row & 7) << 4)));
      }
      #pragma unroll
      for (int mi = 0; mi < 4; mi++)
        #pragma unroll
        for (int ni = 0; ni < 4; ni++)
          acc[mi][ni] = __builtin_amdgcn_mfma_f32_16x16x32_bf16(af[mi], bfr[ni], acc[mi][ni], 0, 0, 0);
    }
  }

  // ---- add xWri, per-row LN stats
  float xw[4], g4[4], b4[4];
  #pragma unroll
  for (int ni = 0; ni < 4; ni++){
    int c = wcol + ni * 16 + llo;
    xw[ni] = xWri[c];
    g4[ni] = gr[c];
    b4[ni] = br[c];
  }
  #pragma unroll
  for (int mi = 0; mi < 4; mi++){
    #pragma unroll
    for (int rr = 0; rr < 4; rr++){
      float sv = 0.f, qv = 0.f;
      #pragma unroll
      for (int ni = 0; ni < 4; ni++){
        float v = acc[mi][ni][rr] + xw[ni];
        acc[mi][ni][rr] = v;
        sv += v; qv += v * v;
      }
      #pragma unroll
      for (int m = 1; m < 16; m <<= 1){
        sv += __shfl_xor(sv, m, 64);
        qv += __shfl_xor(qv, m, 64);
      }
      if (llo == 0){
        int row = mi * 16 + lhi * 4 + rr;
        redS[wid * 64 + row] = sv;
        redQ[wid * 64 + row] = qv;
      }
    }
  }
  __syncthreads();
  if (tid < 64){
    float S = 0.f, Q = 0.f;
    #pragma unroll
    for (int w = 0; w < 8; w++){ S += redS[w * 64 + tid]; Q += redQ[w * 64 + tid]; }
    float mu  = S * (1.f / 512.f);
    float var = Q * (1.f / 512.f) - mu * mu;
    mu_s[tid] = mu;
    rs_s[tid] = rsqrtf(var + 1e-5f);
  }
  __syncthreads();

  // ---- r = sigmoid(LN(v)); psums from h (bf16) in As; reduce over lhi
  float prh[4] = {0.f, 0.f, 0.f, 0.f};
  float ph [4] = {0.f, 0.f, 0.f, 0.f};
  #pragma unroll
  for (int mi = 0; mi < 4; mi++){
    #pragma unroll
    for (int rr = 0; rr < 4; rr++){
      int row = mi * 16 + lhi * 4 + rr;
      float mu = mu_s[row], rs = rs_s[row];
      int sw = (row & 7) << 4;
      #pragma unroll
      for (int ni = 0; ni < 4; ni++){
        float v = (acc[mi][ni][rr] - mu) * rs * g4[ni] + b4[ni];
        float r = 1.f / (1.f + expf(-v));
        int col = wcol + ni * 16 + llo;
        float h = bf2f(*(const unsigned short*)((char*)As + row * 1024 + ((col * 2) ^ sw)));
        prh[ni] += r * h;
        ph [ni] += h;
      }
    }
  }
  #pragma unroll
  for (int ni = 0; ni < 4; ni++){
    prh[ni] += __shfl_xor(prh[ni], 16, 64);
    prh[ni] += __shfl_xor(prh[ni], 32, 64);
    ph [ni] += __shfl_xor(ph [ni], 16, 64);
    ph [ni] += __shfl_xor(ph [ni], 32, 64);
  }
  if (lhi == 0){
    #pragma unroll
    for (int ni = 0; ni < 4; ni++){
      int col = wcol + ni * 16 + llo;
      psum_rh[(size_t)blockIdx.x * HDIM + col] = prh[ni];
      psum_h [(size_t)blockIdx.x * HDIM + col] = ph[ni];
    }
  }
}

// ---------------- kernel 3: reduce partials, build cat vectors ---------------
__global__ __launch_bounds__(256) void reduce_psums(
    const float* __restrict__ psum_rh, const float* __restrict__ psum_h,
    const float* __restrict__ x, float* __restrict__ catz, float* __restrict__ catu,
    int nblk)
{
  __shared__ float L[8][32];
  int b = blockIdx.x, t = threadIdx.x;
  if (b < 32){
    const float* P = (b < 16) ? psum_rh : psum_h;
    int c0 = (b & 15) * 32;
    int wj = t >> 5, ci = t & 31;
    float a = 0.f;
    for (int s = wj; s < nblk; s += 8) a += P[(size_t)s * 512 + c0 + ci];
    L[wj][ci] = a;
    __syncthreads();
    if (t < 32){
      float r = 0.f;
      #pragma unroll
      for (int w = 0; w < 8; w++) r += L[w][t];
      if (b < 16) catu[512 + c0 + t] = r;   // (r*hiddens).sum(0)
      else        catz[512 + c0 + t] = r;   // hidden_sum
    }
  } else {
    int i = ((b - 32) & 1) * 256 + t;       // 0..511
    if (b < 34) catz[i] = x[i];
    else        catu[i] = x[i];
  }
}

// ---------------- kernel 4: zpre = Wz@catz, upre = Wu@catu (one launch) ------
__global__ __launch_bounds__(256) void matvec_zu(
    const float* __restrict__ Wz, const float* __restrict__ Wu,
    const float* __restrict__ catz, const float* __restrict__ catu,
    float* __restrict__ zpre, float* __restrict__ upre)
{
  int b = blockIdx.x, lane = threadIdx.x & 63, wid = threadIdx.x >> 6;
  int row = (b & 127) * 4 + wid;
  const float* W = (b < 128) ? Wz : Wu;
  const float* v = (b < 128) ? catz : catu;
  float*       o = (b < 128) ? zpre : upre;
  const float* Wr = W + (size_t)row * 1024;
  float a = 0.f;
  #pragma unroll
  for (int k = 0; k < 1024 / 64; k++) a += v[k*64 + lane] * Wr[k*64 + lane];
  #pragma unroll
  for (int m = 1; m < 64; m <<= 1) a += __shfl_xor(a, m, 64);
  if (lane == 0) o[row] = a;
}

// ---------------- kernel 5: final LN + gates + output ------------------------
__global__ __launch_bounds__(512) void finalize_k(
    const float* __restrict__ zpre, const float* __restrict__ upre,
    const float* __restrict__ gz, const float* __restrict__ bz,
    const float* __restrict__ gu, const float* __restrict__ bu,
    const float* __restrict__ catz, float* __restrict__ out)
{
  __shared__ float R[8][4];
  int t = threadIdx.x, lane = t & 63, wid = t >> 6;
  float zp = zpre[t], up = upre[t];
  float zs = zp, zq = zp * zp, us = up, uq = up * up;
  #pragma unroll
  for (int m = 1; m < 64; m <<= 1){
    zs += __shfl_xor(zs, m, 64); zq += __shfl_xor(zq, m, 64);
    us += __shfl_xor(us, m, 64); uq += __shfl_xor(uq, m, 64);
  }
  if (lane == 0){ R[wid][0] = zs; R[wid][1] = zq; R[wid][2] = us; R[wid][3] = uq; }
  __syncthreads();
  float ZS = 0.f, ZQ = 0.f, US = 0.f, UQ = 0.f;
  #pragma unroll
  for (int w = 0; w < 8; w++){ ZS += R[w][0]; ZQ += R[w][1]; US += R[w][2]; UQ += R[w][3]; }
  float zmu = ZS / 512.f, zrs = rsqrtf(ZQ / 512.f - zmu * zmu + 1e-5f);
  float umu = US / 512.f, urs = rsqrtf(UQ / 512.f - umu * umu + 1e-5f);
  float z = 1.f / (1.f + expf(-((zp - zmu) * zrs * gz[t] + bz[t])));
  float u = tanhf((up - umu) * urs * gu[t] + bu[t]);
  float hs = catz[512 + t];
  out[t] = z * hs + (1.f - z) * u;
}

// -----------------------------------------------------------------------------
extern "C" void kernel_launch(void* const* d_in, const int* in_sizes, int n_in,
                              void* d_out, int out_size, void* d_ws, size_t ws_size,
                              hipStream_t stream)
{
  const float* x   = (const float*)d_in[0];
  const float* hid = (const float*)d_in[1];
  const float* Wz  = (const float*)d_in[2];
  const float* Wri = (const float*)d_in[3];
  const float* Wrh = (const float*)d_in[4];
  const float* Wu  = (const float*)d_in[5];
  const float* gz  = (const float*)d_in[6];
  const float* bz  = (const float*)d_in[7];
  const float* gr  = (const float*)d_in[8];
  const float* br  = (const float*)d_in[9];
  const float* gu  = (const float*)d_in[10];
  const float* bu  = (const float*)d_in[11];
  (void)n_in; (void)out_size; (void)ws_size;

  const int M    = in_sizes[1] / HDIM;   // 65536
  const int nblk = M / BM;               // 1024

  char* ws = (char*)d_ws;
  unsigned short* wpack = (unsigned short*)ws;              // 512 KB
  float* xwri    = (float*)(ws + 524288);                   // 2 KB
  float* psum_rh = (float*)(ws + 526336);                   // nblk*512*4
  float* psum_h  = (float*)(ws + 526336 + (size_t)nblk * 2048);
  char*  p2      = ws + 526336 + (size_t)nblk * 4096;
  float* catz    = (float*)p2;                              // 4 KB
  float* catu    = (float*)(p2 + 4096);                     // 4 KB
  float* zpre    = (float*)(p2 + 8192);                     // 2 KB
  float* upre    = (float*)(p2 + 10240);                    // 2 KB
  float* out     = (float*)d_out;

  hipLaunchKernelGGL(prep_k,       dim3(256),  dim3(256), 0, stream, Wrh, wpack, Wri, x, xwri);
  hipLaunchKernelGGL(fused_r,      dim3(nblk), dim3(512), 0, stream, hid, wpack, xwri, gr, br, psum_rh, psum_h);
  hipLaunchKernelGGL(reduce_psums, dim3(36),   dim3(256), 0, stream, psum_rh, psum_h, x, catz, catu, nblk);
  hipLaunchKernelGGL(matvec_zu,    dim3(256),  dim3(256), 0, stream, Wz, Wu, catz, catu, zpre, upre);
  hipLaunchKernelGGL(finalize_k,   dim3(1),    dim3(512), 0, stream, zpre, upre, gz, bz, gu, bu, catz, out);
}

// Round 6
// 108.094 us; speedup vs baseline: 1.7585x; 1.0941x over previous
//
#include <hip/hip_runtime.h>

#define HDIM 512
#define BM 64

typedef __attribute__((ext_vector_type(8))) short bf16x8;
typedef __attribute__((ext_vector_type(4))) float f32x4;

__device__ __forceinline__ unsigned short f2bf(float f){
  union { float f; unsigned int u; } c; c.f = f;
  unsigned int u = c.u;
  unsigned int r = u + 0x7fffu + ((u >> 16) & 1u);
  return (unsigned short)(r >> 16);
}
__device__ __forceinline__ float bf2f(unsigned short b){
  union { unsigned int u; float f; } c; c.u = ((unsigned int)b) << 16;
  return c.f;
}
// pack hi16 of two floats (truncation to bf16): out = [bf(b):bf(a)]
__device__ __forceinline__ unsigned int pack_trunc(float a, float b){
  return __builtin_amdgcn_perm(__float_as_uint(b), __float_as_uint(a), 0x07060302u);
}

// ---------------- kernel 1: pack Wrh -> per-wave MFMA fragment order (bf16)
//                  + xwri = Wri @ x
__global__ __launch_bounds__(256) void prep_k(const float* __restrict__ Wrh,
    unsigned short* __restrict__ wpack, const float* __restrict__ Wri,
    const float* __restrict__ x, float* __restrict__ xwri)
{
  int b = blockIdx.x;
  if (b < 128){
    int t    = b * 256 + threadIdx.x;   // 0..32767
    int lane = t & 63;
    int g    = t >> 6;                  // 0..511
    int ni   = g & 3;
    int kkk  = (g >> 2) & 15;
    int wc   = g >> 6;
    int row  = wc * 64 + ni * 16 + (lane & 15);
    int k0   = kkk * 32 + (lane >> 4) * 8;
    const float* src = Wrh + (size_t)row * HDIM + k0;
    float4 f0 = *(const float4*)(src);
    float4 f1 = *(const float4*)(src + 4);
    bf16x8 v;
    v[0]=(short)f2bf(f0.x); v[1]=(short)f2bf(f0.y); v[2]=(short)f2bf(f0.z); v[3]=(short)f2bf(f0.w);
    v[4]=(short)f2bf(f1.x); v[5]=(short)f2bf(f1.y); v[6]=(short)f2bf(f1.z); v[7]=(short)f2bf(f1.w);
    *(bf16x8*)(wpack + (size_t)t * 8) = v;
  } else {
    int lane = threadIdx.x & 63, wid = threadIdx.x >> 6;
    int row = (b - 128) * 4 + wid;
    const float* Wr = Wri + (size_t)row * HDIM;
    float a = 0.f;
    #pragma unroll
    for (int k = 0; k < HDIM / 64; k++) a += x[k*64 + lane] * Wr[k*64 + lane];
    #pragma unroll
    for (int m = 1; m < 64; m <<= 1) a += __shfl_xor(a, m, 64);
    if (lane == 0) xwri[row] = a;
  }
}

// ---------------- kernel 2: fused GEMM + LN + sigmoid + partial sums ---------
__global__ __launch_bounds__(512, 4) void fused_r(
    const float* __restrict__ hiddens,
    const unsigned short* __restrict__ wpack,
    const float* __restrict__ xWri,
    const float* __restrict__ gr, const float* __restrict__ br,
    float* __restrict__ psum_rh, float* __restrict__ psum_h)
{
  __shared__ short As[BM * HDIM];      // 64 KB, [row][col] bf16, byte^((row&7)<<4)
  __shared__ float redS[8 * 64];
  __shared__ float redQ[8 * 64];
  __shared__ float mu_s[64], rs_s[64];

  const int tid  = threadIdx.x;
  const int lane = tid & 63;
  const int wid  = tid >> 6;
  const int llo  = lane & 15;
  const int lhi  = lane >> 4;
  const int wcol = wid * 64;
  const int r0   = blockIdx.x * BM;

  // ---- stage whole A tile (truncation cvt: 1 v_perm per 2 elems)
  {
    int arow = tid >> 3;
    int c0   = (tid & 7) * 8;
    const float* ap = hiddens + (size_t)(r0 + arow) * HDIM + c0;
    char* asb = (char*)As + arow * 1024;
    int sw = (arow & 7) << 4;
    #pragma unroll
    for (int i = 0; i < 8; i++){
      float4 f0 = *(const float4*)(ap + i * 64);
      float4 f1 = *(const float4*)(ap + i * 64 + 4);
      uint4 v;
      v.x = pack_trunc(f0.x, f0.y);
      v.y = pack_trunc(f0.z, f0.w);
      v.z = pack_trunc(f1.x, f1.y);
      v.w = pack_trunc(f1.z, f1.w);
      *(uint4*)(asb + ((c0 * 2 + i * 128) ^ sw)) = v;
    }
  }
  __syncthreads();

  f32x4 acc[4][4];
  #pragma unroll
  for (int i = 0; i < 4; i++)
    #pragma unroll
    for (int j = 0; j < 4; j++)
      #pragma unroll
      for (int k = 0; k < 4; k++) acc[i][j][k] = 0.f;

  // ---- barrier-free K loop: A frags from LDS, B frags coalesced from wpack
  const bf16x8* wp = (const bf16x8*)wpack + ((size_t)wid * 16 * 4) * 64 + lane;
  #pragma unroll 2
  for (int kb = 0; kb < 8; kb++){
    #pragma unroll
    for (int kk = 0; kk < 2; kk++){
      const bf16x8* wpi = wp + (kb * 2 + kk) * 4 * 64;
      bf16x8 af[4], bfr[4];
      #pragma unroll
      for (int ni = 0; ni < 4; ni++)
        bfr[ni] = wpi[ni * 64];
      #pragma unroll
      for (int mi = 0; mi < 4; mi++){
        int row = mi * 16 + llo;
        af[mi] = *(const bf16x8*)((char*)As + row * 1024
                   + ((kb*128 + kk*64 + lhi*16) ^ ((row & 7) << 4)));
      }
      #pragma unroll
      for (int mi = 0; mi < 4; mi++)
        #pragma unroll
        for (int ni = 0; ni < 4; ni++)
          acc[mi][ni] = __builtin_amdgcn_mfma_f32_16x16x32_bf16(af[mi], bfr[ni], acc[mi][ni], 0, 0, 0);
    }
  }

  // ---- add xWri, per-row LN stats
  float xw[4], g4[4], b4[4];
  #pragma unroll
  for (int ni = 0; ni < 4; ni++){
    int c = wcol + ni * 16 + llo;
    xw[ni] = xWri[c];
    g4[ni] = gr[c];
    b4[ni] = br[c];
  }
  #pragma unroll
  for (int mi = 0; mi < 4; mi++){
    #pragma unroll
    for (int rr = 0; rr < 4; rr++){
      float sv = 0.f, qv = 0.f;
      #pragma unroll
      for (int ni = 0; ni < 4; ni++){
        float v = acc[mi][ni][rr] + xw[ni];
        acc[mi][ni][rr] = v;
        sv += v; qv += v * v;
      }
      #pragma unroll
      for (int m = 1; m < 16; m <<= 1){
        sv += __shfl_xor(sv, m, 64);
        qv += __shfl_xor(qv, m, 64);
      }
      if (llo == 0){
        int row = mi * 16 + lhi * 4 + rr;
        redS[wid * 64 + row] = sv;
        redQ[wid * 64 + row] = qv;
      }
    }
  }
  __syncthreads();
  if (tid < 64){
    float S = 0.f, Q = 0.f;
    #pragma unroll
    for (int w = 0; w < 8; w++){ S += redS[w * 64 + tid]; Q += redQ[w * 64 + tid]; }
    float mu  = S * (1.f / 512.f);
    float var = Q * (1.f / 512.f) - mu * mu;
    mu_s[tid] = mu;
    rs_s[tid] = rsqrtf(var + 1e-5f);
  }
  __syncthreads();

  // ---- r = sigmoid(LN(v)) via native exp/rcp; psums from h (bf16) in As
  float prh[4] = {0.f, 0.f, 0.f, 0.f};
  float ph [4] = {0.f, 0.f, 0.f, 0.f};
  #pragma unroll
  for (int mi = 0; mi < 4; mi++){
    #pragma unroll
    for (int rr = 0; rr < 4; rr++){
      int row = mi * 16 + lhi * 4 + rr;
      float mu = mu_s[row], rs = rs_s[row];
      int sw = (row & 7) << 4;
      #pragma unroll
      for (int ni = 0; ni < 4; ni++){
        float v = (acc[mi][ni][rr] - mu) * rs * g4[ni] + b4[ni];
        float r = __builtin_amdgcn_rcpf(1.f + __expf(-v));
        int col = wcol + ni * 16 + llo;
        float h = bf2f(*(const unsigned short*)((char*)As + row * 1024 + ((col * 2) ^ sw)));
        prh[ni] += r * h;
        ph [ni] += h;
      }
    }
  }
  #pragma unroll
  for (int ni = 0; ni < 4; ni++){
    prh[ni] += __shfl_xor(prh[ni], 16, 64);
    prh[ni] += __shfl_xor(prh[ni], 32, 64);
    ph [ni] += __shfl_xor(ph [ni], 16, 64);
    ph [ni] += __shfl_xor(ph [ni], 32, 64);
  }
  if (lhi == 0){
    #pragma unroll
    for (int ni = 0; ni < 4; ni++){
      int col = wcol + ni * 16 + llo;
      psum_rh[(size_t)blockIdx.x * HDIM + col] = prh[ni];
      psum_h [(size_t)blockIdx.x * HDIM + col] = ph[ni];
    }
  }
}

// ---------------- kernel 3: reduce partials, build cat vectors ---------------
__global__ __launch_bounds__(256) void reduce_psums(
    const float* __restrict__ psum_rh, const float* __restrict__ psum_h,
    const float* __restrict__ x, float* __restrict__ catz, float* __restrict__ catu,
    int nblk)
{
  __shared__ float L[8][32];
  int b = blockIdx.x, t = threadIdx.x;
  if (b < 32){
    const float* P = (b < 16) ? psum_rh : psum_h;
    int c0 = (b & 15) * 32;
    int wj = t >> 5, ci = t & 31;
    float a = 0.f;
    for (int s = wj; s < nblk; s += 8) a += P[(size_t)s * 512 + c0 + ci];
    L[wj][ci] = a;
    __syncthreads();
    if (t < 32){
      float r = 0.f;
      #pragma unroll
      for (int w = 0; w < 8; w++) r += L[w][t];
      if (b < 16) catu[512 + c0 + t] = r;   // (r*hiddens).sum(0)
      else        catz[512 + c0 + t] = r;   // hidden_sum
    }
  } else {
    int i = ((b - 32) & 1) * 256 + t;       // 0..511
    if (b < 34) catz[i] = x[i];
    else        catu[i] = x[i];
  }
}

// ---------------- kernel 4: zpre = Wz@catz, upre = Wu@catu (one launch) ------
__global__ __launch_bounds__(256) void matvec_zu(
    const float* __restrict__ Wz, const float* __restrict__ Wu,
    const float* __restrict__ catz, const float* __restrict__ catu,
    float* __restrict__ zpre, float* __restrict__ upre)
{
  int b = blockIdx.x, lane = threadIdx.x & 63, wid = threadIdx.x >> 6;
  int row = (b & 127) * 4 + wid;
  const float* W = (b < 128) ? Wz : Wu;
  const float* v = (b < 128) ? catz : catu;
  float*       o = (b < 128) ? zpre : upre;
  const float* Wr = W + (size_t)row * 1024;
  float a = 0.f;
  #pragma unroll
  for (int k = 0; k < 1024 / 64; k++) a += v[k*64 + lane] * Wr[k*64 + lane];
  #pragma unroll
  for (int m = 1; m < 64; m <<= 1) a += __shfl_xor(a, m, 64);
  if (lane == 0) o[row] = a;
}

// ---------------- kernel 5: final LN + gates + output ------------------------
__global__ __launch_bounds__(512) void finalize_k(
    const float* __restrict__ zpre, const float* __restrict__ upre,
    const float* __restrict__ gz, const float* __restrict__ bz,
    const float* __restrict__ gu, const float* __restrict__ bu,
    const float* __restrict__ catz, float* __restrict__ out)
{
  __shared__ float R[8][4];
  int t = threadIdx.x, lane = t & 63, wid = t >> 6;
  float zp = zpre[t], up = upre[t];
  float zs = zp, zq = zp * zp, us = up, uq = up * up;
  #pragma unroll
  for (int m = 1; m < 64; m <<= 1){
    zs += __shfl_xor(zs, m, 64); zq += __shfl_xor(zq, m, 64);
    us += __shfl_xor(us, m, 64); uq += __shfl_xor(uq, m, 64);
  }
  if (lane == 0){ R[wid][0] = zs; R[wid][1] = zq; R[wid][2] = us; R[wid][3] = uq; }
  __syncthreads();
  float ZS = 0.f, ZQ = 0.f, US = 0.f, UQ = 0.f;
  #pragma unroll
  for (int w = 0; w < 8; w++){ ZS += R[w][0]; ZQ += R[w][1]; US += R[w][2]; UQ += R[w][3]; }
  float zmu = ZS / 512.f, zrs = rsqrtf(ZQ / 512.f - zmu * zmu + 1e-5f);
  float umu = US / 512.f, urs = rsqrtf(UQ / 512.f - umu * umu + 1e-5f);
  float z = 1.f / (1.f + expf(-((zp - zmu) * zrs * gz[t] + bz[t])));
  float u = tanhf((up - umu) * urs * gu[t] + bu[t]);
  float hs = catz[512 + t];
  out[t] = z * hs + (1.f - z) * u;
}

// -----------------------------------------------------------------------------
extern "C" void kernel_launch(void* const* d_in, const int* in_sizes, int n_in,
                              void* d_out, int out_size, void* d_ws, size_t ws_size,
                              hipStream_t stream)
{
  const float* x   = (const float*)d_in[0];
  const float* hid = (const float*)d_in[1];
  const float* Wz  = (const float*)d_in[2];
  const float* Wri = (const float*)d_in[3];
  const float* Wrh = (const float*)d_in[4];
  const float* Wu  = (const float*)d_in[5];
  const float* gz  = (const float*)d_in[6];
  const float* bz  = (const float*)d_in[7];
  const float* gr  = (const float*)d_in[8];
  const float* br  = (const float*)d_in[9];
  const float* gu  = (const float*)d_in[10];
  const float* bu  = (const float*)d_in[11];
  (void)n_in; (void)out_size; (void)ws_size;

  const int M    = in_sizes[1] / HDIM;   // 65536
  const int nblk = M / BM;               // 1024

  char* ws = (char*)d_ws;
  unsigned short* wpack = (unsigned short*)ws;              // 512 KB
  float* xwri    = (float*)(ws + 524288);                   // 2 KB
  float* psum_rh = (float*)(ws + 526336);                   // nblk*512*4
  float* psum_h  = (float*)(ws + 526336 + (size_t)nblk * 2048);
  char*  p2      = ws + 526336 + (size_t)nblk * 4096;
  float* catz    = (float*)p2;                              // 4 KB
  float* catu    = (float*)(p2 + 4096);                     // 4 KB
  float* zpre    = (float*)(p2 + 8192);                     // 2 KB
  float* upre    = (float*)(p2 + 10240);                    // 2 KB
  float* out     = (float*)d_out;

  hipLaunchKernelGGL(prep_k,       dim3(256),  dim3(256), 0, stream, Wrh, wpack, Wri, x, xwri);
  hipLaunchKernelGGL(fused_r,      dim3(nblk), dim3(512), 0, stream, hid, wpack, xwri, gr, br, psum_rh, psum_h);
  hipLaunchKernelGGL(reduce_psums, dim3(36),   dim3(256), 0, stream, psum_rh, psum_h, x, catz, catu, nblk);
  hipLaunchKernelGGL(matvec_zu,    dim3(256),  dim3(256), 0, stream, Wz, Wu, catz, catu, zpre, upre);
  hipLaunchKernelGGL(finalize_k,   dim3(1),    dim3(512), 0, stream, zpre, upre, gz, bz, gu, bu, catz, out);
}

// Round 9
// 105.768 us; speedup vs baseline: 1.7972x; 1.0220x over previous
//
#include <hip/hip_runtime.h>

#define HDIM 512
#define BM 64

typedef __attribute__((ext_vector_type(8))) short bf16x8;
typedef __attribute__((ext_vector_type(4))) float f32x4;

__device__ __forceinline__ unsigned short f2bf(float f){
  union { float f; unsigned int u; } c; c.f = f;
  unsigned int u = c.u;
  unsigned int r = u + 0x7fffu + ((u >> 16) & 1u);
  return (unsigned short)(r >> 16);
}
__device__ __forceinline__ float bf2f(unsigned short b){
  union { unsigned int u; float f; } c; c.u = ((unsigned int)b) << 16;
  return c.f;
}
// pack hi16 of two floats (truncation to bf16): out = [bf(b):bf(a)]
__device__ __forceinline__ unsigned int pack_trunc(float a, float b){
  return __builtin_amdgcn_perm(__float_as_uint(b), __float_as_uint(a), 0x07060302u);
}

// ---------------- kernel 1: pack Wrh -> per-wave MFMA fragment order (bf16)
//                  + xwri = Wri @ x
__global__ __launch_bounds__(256) void prep_k(const float* __restrict__ Wrh,
    unsigned short* __restrict__ wpack, const float* __restrict__ Wri,
    const float* __restrict__ x, float* __restrict__ xwri)
{
  int b = blockIdx.x;
  if (b < 128){
    int t    = b * 256 + threadIdx.x;   // 0..32767
    int lane = t & 63;
    int g    = t >> 6;                  // 0..511
    int ni   = g & 3;
    int kkk  = (g >> 2) & 15;
    int wc   = g >> 6;
    int row  = wc * 64 + ni * 16 + (lane & 15);
    int k0   = kkk * 32 + (lane >> 4) * 8;
    const float* src = Wrh + (size_t)row * HDIM + k0;
    float4 f0 = *(const float4*)(src);
    float4 f1 = *(const float4*)(src + 4);
    bf16x8 v;
    v[0]=(short)f2bf(f0.x); v[1]=(short)f2bf(f0.y); v[2]=(short)f2bf(f0.z); v[3]=(short)f2bf(f0.w);
    v[4]=(short)f2bf(f1.x); v[5]=(short)f2bf(f1.y); v[6]=(short)f2bf(f1.z); v[7]=(short)f2bf(f1.w);
    *(bf16x8*)(wpack + (size_t)t * 8) = v;
  } else {
    int lane = threadIdx.x & 63, wid = threadIdx.x >> 6;
    int row = (b - 128) * 4 + wid;
    const float* Wr = Wri + (size_t)row * HDIM;
    float a = 0.f;
    #pragma unroll
    for (int k = 0; k < HDIM / 64; k++) a += x[k*64 + lane] * Wr[k*64 + lane];
    #pragma unroll
    for (int m = 1; m < 64; m <<= 1) a += __shfl_xor(a, m, 64);
    if (lane == 0) xwri[row] = a;
  }
}

// ---------------- kernel 2: fused GEMM + LN + sigmoid + partial sums ---------
// Slice-pipelined: A (64x512) staged into LDS in 16 K-slices of 32 cols,
// interleaved with the MFMA K-loop. Raw s_barrier (no vmcnt drain) keeps the
// slice-(kb+2) register prefetch in flight across barriers.
__global__ __launch_bounds__(512, 4) void fused_r(
    const float* __restrict__ hiddens,
    const unsigned short* __restrict__ wpack,
    const float* __restrict__ xWri,
    const float* __restrict__ gr, const float* __restrict__ br,
    float* __restrict__ psum_rh, float* __restrict__ psum_h)
{
  __shared__ short As[BM * HDIM];      // 64 KB, [row][col] bf16, byte^((row&7)<<4)
  __shared__ float redS[8 * 64];
  __shared__ float redQ[8 * 64];
  __shared__ float mu_s[64], rs_s[64];

  const int tid  = threadIdx.x;
  const int lane = tid & 63;
  const int wid  = tid >> 6;
  const int llo  = lane & 15;
  const int lhi  = lane >> 4;
  const int wcol = wid * 64;
  const int r0   = blockIdx.x * BM;

  // staging mapping: thread -> row tid>>3, 4 floats at col (tid&7)*4 of each slice
  const int arow = tid >> 3;
  const int ac8  = (tid & 7) * 8;           // byte offset of 4 bf16 within slice row
  const float* aslice = hiddens + (size_t)(r0 + arow) * HDIM + (tid & 7) * 4;
  char* asb = (char*)As + arow * 1024;
  const int sw = (arow & 7) << 4;

  f32x4 acc[4][4];
  #pragma unroll
  for (int i = 0; i < 4; i++)
    #pragma unroll
    for (int j = 0; j < 4; j++)
      #pragma unroll
      for (int k = 0; k < 4; k++) acc[i][j][k] = 0.f;

  // ---- prologue: prefetch slices 0,1; write slice 0; barrier
  float4 pref0 = *(const float4*)(aslice);
  float4 pref1 = *(const float4*)(aslice + 32);
  {
    uint2 w; w.x = pack_trunc(pref0.x, pref0.y); w.y = pack_trunc(pref0.z, pref0.w);
    *(uint2*)(asb + (ac8 ^ sw)) = w;
  }
  asm volatile("s_waitcnt lgkmcnt(0)" ::: "memory");
  __builtin_amdgcn_s_barrier();

  // ---- pipelined K loop: 16 slices of K=32
  const bf16x8* wp = (const bf16x8*)wpack + ((size_t)wid * 16 * 4) * 64 + lane;
  #pragma unroll 2
  for (int kb = 0; kb < 16; kb++){
    // B frags for this slice (coalesced, L2-resident)
    const bf16x8* wpi = wp + kb * 4 * 64;
    bf16x8 bfr[4];
    #pragma unroll
    for (int ni = 0; ni < 4; ni++) bfr[ni] = wpi[ni * 64];
    // register prefetch of slice kb+2
    if ((kb & 1) == 0){ if (kb + 2 < 16) pref0 = *(const float4*)(aslice + (kb + 2) * 32); }
    else              { if (kb + 2 < 16) pref1 = *(const float4*)(aslice + (kb + 2) * 32); }
    // A frags for slice kb from LDS
    bf16x8 af[4];
    #pragma unroll
    for (int mi = 0; mi < 4; mi++){
      int row = mi * 16 + llo;
      af[mi] = *(const bf16x8*)((char*)As + row * 1024
                 + ((kb * 64 + lhi * 16) ^ ((row & 7) << 4)));
    }
    #pragma unroll
    for (int mi = 0; mi < 4; mi++)
      #pragma unroll
      for (int ni = 0; ni < 4; ni++)
        acc[mi][ni] = __builtin_amdgcn_mfma_f32_16x16x32_bf16(af[mi], bfr[ni], acc[mi][ni], 0, 0, 0);
    // stage slice kb+1 (data prefetched last iter)
    if (kb + 1 < 16){
      float4 p = ((kb + 1) & 1) ? pref1 : pref0;
      uint2 w; w.x = pack_trunc(p.x, p.y); w.y = pack_trunc(p.z, p.w);
      *(uint2*)(asb + (((kb + 1) * 64 + ac8) ^ sw)) = w;
    }
    asm volatile("s_waitcnt lgkmcnt(0)" ::: "memory");
    __builtin_amdgcn_s_barrier();
  }

  // ---- add xWri, per-row LN stats
  float xw[4], g4[4], b4[4];
  #pragma unroll
  for (int ni = 0; ni < 4; ni++){
    int c = wcol + ni * 16 + llo;
    xw[ni] = xWri[c];
    g4[ni] = gr[c];
    b4[ni] = br[c];
  }
  #pragma unroll
  for (int mi = 0; mi < 4; mi++){
    #pragma unroll
    for (int rr = 0; rr < 4; rr++){
      float sv = 0.f, qv = 0.f;
      #pragma unroll
      for (int ni = 0; ni < 4; ni++){
        float v = acc[mi][ni][rr] + xw[ni];
        acc[mi][ni][rr] = v;
        sv += v; qv += v * v;
      }
      #pragma unroll
      for (int m = 1; m < 16; m <<= 1){
        sv += __shfl_xor(sv, m, 64);
        qv += __shfl_xor(qv, m, 64);
      }
      if (llo == 0){
        int row = mi * 16 + lhi * 4 + rr;
        redS[wid * 64 + row] = sv;
        redQ[wid * 64 + row] = qv;
      }
    }
  }
  __syncthreads();
  if (tid < 64){
    float S = 0.f, Q = 0.f;
    #pragma unroll
    for (int w = 0; w < 8; w++){ S += redS[w * 64 + tid]; Q += redQ[w * 64 + tid]; }
    float mu  = S * (1.f / 512.f);
    float var = Q * (1.f / 512.f) - mu * mu;
    mu_s[tid] = mu;
    rs_s[tid] = rsqrtf(var + 1e-5f);
  }
  __syncthreads();

  // ---- r = sigmoid(LN(v)) via native exp/rcp; psums from h (bf16) in As
  float prh[4] = {0.f, 0.f, 0.f, 0.f};
  float ph [4] = {0.f, 0.f, 0.f, 0.f};
  #pragma unroll
  for (int mi = 0; mi < 4; mi++){
    #pragma unroll
    for (int rr = 0; rr < 4; rr++){
      int row = mi * 16 + lhi * 4 + rr;
      float mu = mu_s[row], rs = rs_s[row];
      int sw2 = (row & 7) << 4;
      #pragma unroll
      for (int ni = 0; ni < 4; ni++){
        float v = (acc[mi][ni][rr] - mu) * rs * g4[ni] + b4[ni];
        float r = __builtin_amdgcn_rcpf(1.f + __expf(-v));
        int col = wcol + ni * 16 + llo;
        float h = bf2f(*(const unsigned short*)((char*)As + row * 1024 + ((col * 2) ^ sw2)));
        prh[ni] += r * h;
        ph [ni] += h;
      }
    }
  }
  #pragma unroll
  for (int ni = 0; ni < 4; ni++){
    prh[ni] += __shfl_xor(prh[ni], 16, 64);
    prh[ni] += __shfl_xor(prh[ni], 32, 64);
    ph [ni] += __shfl_xor(ph [ni], 16, 64);
    ph [ni] += __shfl_xor(ph [ni], 32, 64);
  }
  if (lhi == 0){
    #pragma unroll
    for (int ni = 0; ni < 4; ni++){
      int col = wcol + ni * 16 + llo;
      psum_rh[(size_t)blockIdx.x * HDIM + col] = prh[ni];
      psum_h [(size_t)blockIdx.x * HDIM + col] = ph[ni];
    }
  }
}

// ---------------- kernel 3: reduce partials, build cat vectors ---------------
__global__ __launch_bounds__(256) void reduce_psums(
    const float* __restrict__ psum_rh, const float* __restrict__ psum_h,
    const float* __restrict__ x, float* __restrict__ catz, float* __restrict__ catu,
    int nblk)
{
  __shared__ float L[8][32];
  int b = blockIdx.x, t = threadIdx.x;
  if (b < 32){
    const float* P = (b < 16) ? psum_rh : psum_h;
    int c0 = (b & 15) * 32;
    int wj = t >> 5, ci = t & 31;
    float a = 0.f;
    for (int s = wj; s < nblk; s += 8) a += P[(size_t)s * 512 + c0 + ci];
    L[wj][ci] = a;
    __syncthreads();
    if (t < 32){
      float r = 0.f;
      #pragma unroll
      for (int w = 0; w < 8; w++) r += L[w][t];
      if (b < 16) catu[512 + c0 + t] = r;   // (r*hiddens).sum(0)
      else        catz[512 + c0 + t] = r;   // hidden_sum
    }
  } else {
    int i = ((b - 32) & 1) * 256 + t;       // 0..511
    if (b < 34) catz[i] = x[i];
    else        catu[i] = x[i];
  }
}

// ---------------- kernel 4: zpre = Wz@catz, upre = Wu@catu (one launch) ------
__global__ __launch_bounds__(256) void matvec_zu(
    const float* __restrict__ Wz, const float* __restrict__ Wu,
    const float* __restrict__ catz, const float* __restrict__ catu,
    float* __restrict__ zpre, float* __restrict__ upre)
{
  int b = blockIdx.x, lane = threadIdx.x & 63, wid = threadIdx.x >> 6;
  int row = (b & 127) * 4 + wid;
  const float* W = (b < 128) ? Wz : Wu;
  const float* v = (b < 128) ? catz : catu;
  float*       o = (b < 128) ? zpre : upre;
  const float* Wr = W + (size_t)row * 1024;
  float a = 0.f;
  #pragma unroll
  for (int k = 0; k < 1024 / 64; k++) a += v[k*64 + lane] * Wr[k*64 + lane];
  #pragma unroll
  for (int m = 1; m < 64; m <<= 1) a += __shfl_xor(a, m, 64);
  if (lane == 0) o[row] = a;
}

// ---------------- kernel 5: final LN + gates + output ------------------------
__global__ __launch_bounds__(512) void finalize_k(
    const float* __restrict__ zpre, const float* __restrict__ upre,
    const float* __restrict__ gz, const float* __restrict__ bz,
    const float* __restrict__ gu, const float* __restrict__ bu,
    const float* __restrict__ catz, float* __restrict__ out)
{
  __shared__ float R[8][4];
  int t = threadIdx.x, lane = t & 63, wid = t >> 6;
  float zp = zpre[t], up = upre[t];
  float zs = zp, zq = zp * zp, us = up, uq = up * up;
  #pragma unroll
  for (int m = 1; m < 64; m <<= 1){
    zs += __shfl_xor(zs, m, 64); zq += __shfl_xor(zq, m, 64);
    us += __shfl_xor(us, m, 64); uq += __shfl_xor(uq, m, 64);
  }
  if (lane == 0){ R[wid][0] = zs; R[wid][1] = zq; R[wid][2] = us; R[wid][3] = uq; }
  __syncthreads();
  float ZS = 0.f, ZQ = 0.f, US = 0.f, UQ = 0.f;
  #pragma unroll
  for (int w = 0; w < 8; w++){ ZS += R[w][0]; ZQ += R[w][1]; US += R[w][2]; UQ += R[w][3]; }
  float zmu = ZS / 512.f, zrs = rsqrtf(ZQ / 512.f - zmu * zmu + 1e-5f);
  float umu = US / 512.f, urs = rsqrtf(UQ / 512.f - umu * umu + 1e-5f);
  float z = 1.f / (1.f + expf(-((zp - zmu) * zrs * gz[t] + bz[t])));
  float u = tanhf((up - umu) * urs * gu[t] + bu[t]);
  float hs = catz[512 + t];
  out[t] = z * hs + (1.f - z) * u;
}

// -----------------------------------------------------------------------------
extern "C" void kernel_launch(void* const* d_in, const int* in_sizes, int n_in,
                              void* d_out, int out_size, void* d_ws, size_t ws_size,
                              hipStream_t stream)
{
  const float* x   = (const float*)d_in[0];
  const float* hid = (const float*)d_in[1];
  const float* Wz  = (const float*)d_in[2];
  const float* Wri = (const float*)d_in[3];
  const float* Wrh = (const float*)d_in[4];
  const float* Wu  = (const float*)d_in[5];
  const float* gz  = (const float*)d_in[6];
  const float* bz  = (const float*)d_in[7];
  const float* gr  = (const float*)d_in[8];
  const float* br  = (const float*)d_in[9];
  const float* gu  = (const float*)d_in[10];
  const float* bu  = (const float*)d_in[11];
  (void)n_in; (void)out_size; (void)ws_size;

  const int M    = in_sizes[1] / HDIM;   // 65536
  const int nblk = M / BM;               // 1024

  char* ws = (char*)d_ws;
  unsigned short* wpack = (unsigned short*)ws;              // 512 KB
  float* xwri    = (float*)(ws + 524288);                   // 2 KB
  float* psum_rh = (float*)(ws + 526336);                   // nblk*512*4
  float* psum_h  = (float*)(ws + 526336 + (size_t)nblk * 2048);
  char*  p2      = ws + 526336 + (size_t)nblk * 4096;
  float* catz    = (float*)p2;                              // 4 KB
  float* catu    = (float*)(p2 + 4096);                     // 4 KB
  float* zpre    = (float*)(p2 + 8192);                     // 2 KB
  float* upre    = (float*)(p2 + 10240);                    // 2 KB
  float* out     = (float*)d_out;

  hipLaunchKernelGGL(prep_k,       dim3(256),  dim3(256), 0, stream, Wrh, wpack, Wri, x, xwri);
  hipLaunchKernelGGL(fused_r,      dim3(nblk), dim3(512), 0, stream, hid, wpack, xwri, gr, br, psum_rh, psum_h);
  hipLaunchKernelGGL(reduce_psums, dim3(36),   dim3(256), 0, stream, psum_rh, psum_h, x, catz, catu, nblk);
  hipLaunchKernelGGL(matvec_zu,    dim3(256),  dim3(256), 0, stream, Wz, Wu, catz, catu, zpre, upre);
  hipLaunchKernelGGL(finalize_k,   dim3(1),    dim3(512), 0, stream, zpre, upre, gz, bz, gu, bu, catz, out);
}

// Round 10
// 104.210 us; speedup vs baseline: 1.8241x; 1.0149x over previous
//
#include <hip/hip_runtime.h>

#define HDIM 512
#define BM 64

typedef __attribute__((ext_vector_type(8))) short bf16x8;
typedef __attribute__((ext_vector_type(4))) float f32x4;

__device__ __forceinline__ unsigned short f2bf(float f){
  union { float f; unsigned int u; } c; c.f = f;
  unsigned int u = c.u;
  unsigned int r = u + 0x7fffu + ((u >> 16) & 1u);
  return (unsigned short)(r >> 16);
}
__device__ __forceinline__ float bf2f(unsigned short b){
  union { unsigned int u; float f; } c; c.u = ((unsigned int)b) << 16;
  return c.f;
}
// pack hi16 of two floats (truncation to bf16): out = [bf(b):bf(a)]
__device__ __forceinline__ unsigned int pack_trunc(float a, float b){
  return __builtin_amdgcn_perm(__float_as_uint(b), __float_as_uint(a), 0x07060302u);
}

// ---------------- kernel 1: pack Wrh -> per-wave MFMA fragment order (bf16)
//                  + xwri = Wri @ x
__global__ __launch_bounds__(256) void prep_k(const float* __restrict__ Wrh,
    unsigned short* __restrict__ wpack, const float* __restrict__ Wri,
    const float* __restrict__ x, float* __restrict__ xwri)
{
  int b = blockIdx.x;
  if (b < 128){
    int t    = b * 256 + threadIdx.x;   // 0..32767
    int lane = t & 63;
    int g    = t >> 6;                  // 0..511
    int ni   = g & 3;
    int kkk  = (g >> 2) & 15;
    int wc   = g >> 6;
    int row  = wc * 64 + ni * 16 + (lane & 15);
    int k0   = kkk * 32 + (lane >> 4) * 8;
    const float* src = Wrh + (size_t)row * HDIM + k0;
    float4 f0 = *(const float4*)(src);
    float4 f1 = *(const float4*)(src + 4);
    bf16x8 v;
    v[0]=(short)f2bf(f0.x); v[1]=(short)f2bf(f0.y); v[2]=(short)f2bf(f0.z); v[3]=(short)f2bf(f0.w);
    v[4]=(short)f2bf(f1.x); v[5]=(short)f2bf(f1.y); v[6]=(short)f2bf(f1.z); v[7]=(short)f2bf(f1.w);
    *(bf16x8*)(wpack + (size_t)t * 8) = v;
  } else {
    int lane = threadIdx.x & 63, wid = threadIdx.x >> 6;
    int row = (b - 128) * 4 + wid;
    const float* Wr = Wri + (size_t)row * HDIM;
    float a = 0.f;
    #pragma unroll
    for (int k = 0; k < HDIM / 64; k++) a += x[k*64 + lane] * Wr[k*64 + lane];
    #pragma unroll
    for (int m = 1; m < 64; m <<= 1) a += __shfl_xor(a, m, 64);
    if (lane == 0) xwri[row] = a;
  }
}

// ---------------- kernel 2: fused GEMM + LN + sigmoid + partial sums ---------
// Slice-pipelined: A staged into LDS in 16 K-slices of 32 cols; B (wpack)
// software-pipelined ONE SLICE AHEAD in registers (loads issued after last
// MFMA use -> same regs, stay in flight across the raw s_barrier).
__global__ __launch_bounds__(512, 4) void fused_r(
    const float* __restrict__ hiddens,
    const unsigned short* __restrict__ wpack,
    const float* __restrict__ xWri,
    const float* __restrict__ gr, const float* __restrict__ br,
    float* __restrict__ psum_rh, float* __restrict__ psum_h)
{
  __shared__ short As[BM * HDIM];      // 64 KB, [row][col] bf16, byte^((row&7)<<4)
  __shared__ float redS[8 * 64];
  __shared__ float redQ[8 * 64];
  __shared__ float mu_s[64], rs_s[64];

  const int tid  = threadIdx.x;
  const int lane = tid & 63;
  const int wid  = tid >> 6;
  const int llo  = lane & 15;
  const int lhi  = lane >> 4;
  const int wcol = wid * 64;
  const int r0   = blockIdx.x * BM;

  // staging mapping: thread -> row tid>>3, 4 floats at col (tid&7)*4 of each slice
  const int arow = tid >> 3;
  const int ac8  = (tid & 7) * 8;           // byte offset of 4 bf16 within slice row
  const float* aslice = hiddens + (size_t)(r0 + arow) * HDIM + (tid & 7) * 4;
  char* asb = (char*)As + arow * 1024;
  const int sw = (arow & 7) << 4;

  f32x4 acc[4][4];
  #pragma unroll
  for (int i = 0; i < 4; i++)
    #pragma unroll
    for (int j = 0; j < 4; j++)
      #pragma unroll
      for (int k = 0; k < 4; k++) acc[i][j][k] = 0.f;

  // ---- prologue: prefetch A slices 0,1; B fragments slice 0; write A slice 0
  float4 pref0 = *(const float4*)(aslice);
  float4 pref1 = *(const float4*)(aslice + 32);
  const bf16x8* wp = (const bf16x8*)wpack + ((size_t)wid * 16 * 4) * 64 + lane;
  bf16x8 bfr[4];
  #pragma unroll
  for (int ni = 0; ni < 4; ni++) bfr[ni] = wp[ni * 64];
  {
    uint2 w; w.x = pack_trunc(pref0.x, pref0.y); w.y = pack_trunc(pref0.z, pref0.w);
    *(uint2*)(asb + (ac8 ^ sw)) = w;
  }
  asm volatile("s_waitcnt lgkmcnt(0)" ::: "memory");
  __builtin_amdgcn_s_barrier();

  // ---- pipelined K loop: 16 slices of K=32
  #pragma unroll 2
  for (int kb = 0; kb < 16; kb++){
    // A frags for slice kb from LDS
    bf16x8 af[4];
    #pragma unroll
    for (int mi = 0; mi < 4; mi++){
      int row = mi * 16 + llo;
      af[mi] = *(const bf16x8*)((char*)As + row * 1024
                 + ((kb * 64 + lhi * 16) ^ ((row & 7) << 4)));
    }
    // register prefetch of A slice kb+2
    if ((kb & 1) == 0){ if (kb + 2 < 16) pref0 = *(const float4*)(aslice + (kb + 2) * 32); }
    else              { if (kb + 2 < 16) pref1 = *(const float4*)(aslice + (kb + 2) * 32); }
    // MFMAs consume bfr (loaded one slice ago)
    #pragma unroll
    for (int mi = 0; mi < 4; mi++)
      #pragma unroll
      for (int ni = 0; ni < 4; ni++)
        acc[mi][ni] = __builtin_amdgcn_mfma_f32_16x16x32_bf16(af[mi], bfr[ni], acc[mi][ni], 0, 0, 0);
    // B prefetch for slice kb+1 (after last bfr use; in flight across barrier)
    if (kb + 1 < 16){
      const bf16x8* wpn = wp + (kb + 1) * 4 * 64;
      #pragma unroll
      for (int ni = 0; ni < 4; ni++) bfr[ni] = wpn[ni * 64];
    }
    // stage A slice kb+1 (data prefetched last iter)
    if (kb + 1 < 16){
      float4 p = ((kb + 1) & 1) ? pref1 : pref0;
      uint2 w; w.x = pack_trunc(p.x, p.y); w.y = pack_trunc(p.z, p.w);
      *(uint2*)(asb + (((kb + 1) * 64 + ac8) ^ sw)) = w;
    }
    asm volatile("s_waitcnt lgkmcnt(0)" ::: "memory");
    __builtin_amdgcn_s_barrier();
  }

  // ---- add xWri, per-row LN stats
  float xw[4], g4[4], b4[4];
  #pragma unroll
  for (int ni = 0; ni < 4; ni++){
    int c = wcol + ni * 16 + llo;
    xw[ni] = xWri[c];
    g4[ni] = gr[c];
    b4[ni] = br[c];
  }
  #pragma unroll
  for (int mi = 0; mi < 4; mi++){
    #pragma unroll
    for (int rr = 0; rr < 4; rr++){
      float sv = 0.f, qv = 0.f;
      #pragma unroll
      for (int ni = 0; ni < 4; ni++){
        float v = acc[mi][ni][rr] + xw[ni];
        acc[mi][ni][rr] = v;
        sv += v; qv += v * v;
      }
      #pragma unroll
      for (int m = 1; m < 16; m <<= 1){
        sv += __shfl_xor(sv, m, 64);
        qv += __shfl_xor(qv, m, 64);
      }
      if (llo == 0){
        int row = mi * 16 + lhi * 4 + rr;
        redS[wid * 64 + row] = sv;
        redQ[wid * 64 + row] = qv;
      }
    }
  }
  __syncthreads();
  if (tid < 64){
    float S = 0.f, Q = 0.f;
    #pragma unroll
    for (int w = 0; w < 8; w++){ S += redS[w * 64 + tid]; Q += redQ[w * 64 + tid]; }
    float mu  = S * (1.f / 512.f);
    float var = Q * (1.f / 512.f) - mu * mu;
    mu_s[tid] = mu;
    rs_s[tid] = rsqrtf(var + 1e-5f);
  }
  __syncthreads();

  // ---- r = sigmoid(LN(v)) via native exp/rcp; psums from h (bf16) in As
  float prh[4] = {0.f, 0.f, 0.f, 0.f};
  float ph [4] = {0.f, 0.f, 0.f, 0.f};
  #pragma unroll
  for (int mi = 0; mi < 4; mi++){
    #pragma unroll
    for (int rr = 0; rr < 4; rr++){
      int row = mi * 16 + lhi * 4 + rr;
      float mu = mu_s[row], rs = rs_s[row];
      int sw2 = (row & 7) << 4;
      #pragma unroll
      for (int ni = 0; ni < 4; ni++){
        float v = (acc[mi][ni][rr] - mu) * rs * g4[ni] + b4[ni];
        float r = __builtin_amdgcn_rcpf(1.f + __expf(-v));
        int col = wcol + ni * 16 + llo;
        float h = bf2f(*(const unsigned short*)((char*)As + row * 1024 + ((col * 2) ^ sw2)));
        prh[ni] += r * h;
        ph [ni] += h;
      }
    }
  }
  #pragma unroll
  for (int ni = 0; ni < 4; ni++){
    prh[ni] += __shfl_xor(prh[ni], 16, 64);
    prh[ni] += __shfl_xor(prh[ni], 32, 64);
    ph [ni] += __shfl_xor(ph [ni], 16, 64);
    ph [ni] += __shfl_xor(ph [ni], 32, 64);
  }
  if (lhi == 0){
    #pragma unroll
    for (int ni = 0; ni < 4; ni++){
      int col = wcol + ni * 16 + llo;
      psum_rh[(size_t)blockIdx.x * HDIM + col] = prh[ni];
      psum_h [(size_t)blockIdx.x * HDIM + col] = ph[ni];
    }
  }
}

// ---------------- kernel 3: reduce partials, build cat vectors ---------------
__global__ __launch_bounds__(256) void reduce_psums(
    const float* __restrict__ psum_rh, const float* __restrict__ psum_h,
    const float* __restrict__ x, float* __restrict__ catz, float* __restrict__ catu,
    int nblk)
{
  __shared__ float L[8][32];
  int b = blockIdx.x, t = threadIdx.x;
  if (b < 32){
    const float* P = (b < 16) ? psum_rh : psum_h;
    int c0 = (b & 15) * 32;
    int wj = t >> 5, ci = t & 31;
    float a = 0.f;
    for (int s = wj; s < nblk; s += 8) a += P[(size_t)s * 512 + c0 + ci];
    L[wj][ci] = a;
    __syncthreads();
    if (t < 32){
      float r = 0.f;
      #pragma unroll
      for (int w = 0; w < 8; w++) r += L[w][t];
      if (b < 16) catu[512 + c0 + t] = r;   // (r*hiddens).sum(0)
      else        catz[512 + c0 + t] = r;   // hidden_sum
    }
  } else {
    int i = ((b - 32) & 1) * 256 + t;       // 0..511
    if (b < 34) catz[i] = x[i];
    else        catu[i] = x[i];
  }
}

// ---------------- kernel 4: zpre = Wz@catz, upre = Wu@catu (one launch) ------
__global__ __launch_bounds__(256) void matvec_zu(
    const float* __restrict__ Wz, const float* __restrict__ Wu,
    const float* __restrict__ catz, const float* __restrict__ catu,
    float* __restrict__ zpre, float* __restrict__ upre)
{
  int b = blockIdx.x, lane = threadIdx.x & 63, wid = threadIdx.x >> 6;
  int row = (b & 127) * 4 + wid;
  const float* W = (b < 128) ? Wz : Wu;
  const float* v = (b < 128) ? catz : catu;
  float*       o = (b < 128) ? zpre : upre;
  const float* Wr = W + (size_t)row * 1024;
  float a = 0.f;
  #pragma unroll
  for (int k = 0; k < 1024 / 64; k++) a += v[k*64 + lane] * Wr[k*64 + lane];
  #pragma unroll
  for (int m = 1; m < 64; m <<= 1) a += __shfl_xor(a, m, 64);
  if (lane == 0) o[row] = a;
}

// ---------------- kernel 5: final LN + gates + output ------------------------
__global__ __launch_bounds__(512) void finalize_k(
    const float* __restrict__ zpre, const float* __restrict__ upre,
    const float* __restrict__ gz, const float* __restrict__ bz,
    const float* __restrict__ gu, const float* __restrict__ bu,
    const float* __restrict__ catz, float* __restrict__ out)
{
  __shared__ float R[8][4];
  int t = threadIdx.x, lane = t & 63, wid = t >> 6;
  float zp = zpre[t], up = upre[t];
  float zs = zp, zq = zp * zp, us = up, uq = up * up;
  #pragma unroll
  for (int m = 1; m < 64; m <<= 1){
    zs += __shfl_xor(zs, m, 64); zq += __shfl_xor(zq, m, 64);
    us += __shfl_xor(us, m, 64); uq += __shfl_xor(uq, m, 64);
  }
  if (lane == 0){ R[wid][0] = zs; R[wid][1] = zq; R[wid][2] = us; R[wid][3] = uq; }
  __syncthreads();
  float ZS = 0.f, ZQ = 0.f, US = 0.f, UQ = 0.f;
  #pragma unroll
  for (int w = 0; w < 8; w++){ ZS += R[w][0]; ZQ += R[w][1]; US += R[w][2]; UQ += R[w][3]; }
  float zmu = ZS / 512.f, zrs = rsqrtf(ZQ / 512.f - zmu * zmu + 1e-5f);
  float umu = US / 512.f, urs = rsqrtf(UQ / 512.f - umu * umu + 1e-5f);
  float z = 1.f / (1.f + expf(-((zp - zmu) * zrs * gz[t] + bz[t])));
  float u = tanhf((up - umu) * urs * gu[t] + bu[t]);
  float hs = catz[512 + t];
  out[t] = z * hs + (1.f - z) * u;
}

// -----------------------------------------------------------------------------
extern "C" void kernel_launch(void* const* d_in, const int* in_sizes, int n_in,
                              void* d_out, int out_size, void* d_ws, size_t ws_size,
                              hipStream_t stream)
{
  const float* x   = (const float*)d_in[0];
  const float* hid = (const float*)d_in[1];
  const float* Wz  = (const float*)d_in[2];
  const float* Wri = (const float*)d_in[3];
  const float* Wrh = (const float*)d_in[4];
  const float* Wu  = (const float*)d_in[5];
  const float* gz  = (const float*)d_in[6];
  const float* bz  = (const float*)d_in[7];
  const float* gr  = (const float*)d_in[8];
  const float* br  = (const float*)d_in[9];
  const float* gu  = (const float*)d_in[10];
  const float* bu  = (const float*)d_in[11];
  (void)n_in; (void)out_size; (void)ws_size;

  const int M    = in_sizes[1] / HDIM;   // 65536
  const int nblk = M / BM;               // 1024

  char* ws = (char*)d_ws;
  unsigned short* wpack = (unsigned short*)ws;              // 512 KB
  float* xwri    = (float*)(ws + 524288);                   // 2 KB
  float* psum_rh = (float*)(ws + 526336);                   // nblk*512*4
  float* psum_h  = (float*)(ws + 526336 + (size_t)nblk * 2048);
  char*  p2      = ws + 526336 + (size_t)nblk * 4096;
  float* catz    = (float*)p2;                              // 4 KB
  float* catu    = (float*)(p2 + 4096);                     // 4 KB
  float* zpre    = (float*)(p2 + 8192);                     // 2 KB
  float* upre    = (float*)(p2 + 10240);                    // 2 KB
  float* out     = (float*)d_out;

  hipLaunchKernelGGL(prep_k,       dim3(256),  dim3(256), 0, stream, Wrh, wpack, Wri, x, xwri);
  hipLaunchKernelGGL(fused_r,      dim3(nblk), dim3(512), 0, stream, hid, wpack, xwri, gr, br, psum_rh, psum_h);
  hipLaunchKernelGGL(reduce_psums, dim3(36),   dim3(256), 0, stream, psum_rh, psum_h, x, catz, catu, nblk);
  hipLaunchKernelGGL(matvec_zu,    dim3(256),  dim3(256), 0, stream, Wz, Wu, catz, catu, zpre, upre);
  hipLaunchKernelGGL(finalize_k,   dim3(1),    dim3(512), 0, stream, zpre, upre, gz, bz, gu, bu, catz, out);
}

// Round 11
// 94.500 us; speedup vs baseline: 2.0115x; 1.1028x over previous
//
#include <hip/hip_runtime.h>

#define HDIM 512
#define BM 128

typedef __attribute__((ext_vector_type(8))) short bf16x8;
typedef __attribute__((ext_vector_type(4))) float f32x4;

__device__ __forceinline__ unsigned short f2bf(float f){
  union { float f; unsigned int u; } c; c.f = f;
  unsigned int u = c.u;
  unsigned int r = u + 0x7fffu + ((u >> 16) & 1u);
  return (unsigned short)(r >> 16);
}
__device__ __forceinline__ float bf2f(unsigned short b){
  union { unsigned int u; float f; } c; c.u = ((unsigned int)b) << 16;
  return c.f;
}
// pack hi16 of two floats (truncation to bf16): out = [bf(b):bf(a)]
__device__ __forceinline__ unsigned int pack_trunc(float a, float b){
  return __builtin_amdgcn_perm(__float_as_uint(b), __float_as_uint(a), 0x07060302u);
}

// ---------------- kernel 1: pack Wrh -> per-wave MFMA fragment order (bf16)
//                  + xwri = Wri @ x
__global__ __launch_bounds__(256) void prep_k(const float* __restrict__ Wrh,
    unsigned short* __restrict__ wpack, const float* __restrict__ Wri,
    const float* __restrict__ x, float* __restrict__ xwri)
{
  int b = blockIdx.x;
  if (b < 128){
    int t    = b * 256 + threadIdx.x;   // 0..32767
    int lane = t & 63;
    int g    = t >> 6;                  // 0..511
    int ni   = g & 3;
    int kkk  = (g >> 2) & 15;
    int wc   = g >> 6;
    int row  = wc * 64 + ni * 16 + (lane & 15);
    int k0   = kkk * 32 + (lane >> 4) * 8;
    const float* src = Wrh + (size_t)row * HDIM + k0;
    float4 f0 = *(const float4*)(src);
    float4 f1 = *(const float4*)(src + 4);
    bf16x8 v;
    v[0]=(short)f2bf(f0.x); v[1]=(short)f2bf(f0.y); v[2]=(short)f2bf(f0.z); v[3]=(short)f2bf(f0.w);
    v[4]=(short)f2bf(f1.x); v[5]=(short)f2bf(f1.y); v[6]=(short)f2bf(f1.z); v[7]=(short)f2bf(f1.w);
    *(bf16x8*)(wpack + (size_t)t * 8) = v;
  } else {
    int lane = threadIdx.x & 63, wid = threadIdx.x >> 6;
    int row = (b - 128) * 4 + wid;
    const float* Wr = Wri + (size_t)row * HDIM;
    float a = 0.f;
    #pragma unroll
    for (int k = 0; k < HDIM / 64; k++) a += x[k*64 + lane] * Wr[k*64 + lane];
    #pragma unroll
    for (int m = 1; m < 64; m <<= 1) a += __shfl_xor(a, m, 64);
    if (lane == 0) xwri[row] = a;
  }
}

// ---------------- kernel 2: fused GEMM + LN + sigmoid + partial sums ---------
// BM=128, 1024 threads = 16 waves (2 rowgrp x 8 colgrp); each wave 64x64.
// Doubles B reuse per fetch (B-L2 traffic halves vs BM=64). A staged in LDS
// slice-by-slice (16 K-slices of 32), B 1-slice-ahead in regs, A 2-ahead.
__global__ __launch_bounds__(1024, 4) void fused_r(
    const float* __restrict__ hiddens,
    const unsigned short* __restrict__ wpack,
    const float* __restrict__ xWri,
    const float* __restrict__ gr, const float* __restrict__ br,
    float* __restrict__ psum_rh, float* __restrict__ psum_h)
{
  __shared__ short As[BM * HDIM];      // 128 KB, [row][col] bf16, byte^((row&7)<<4)
  __shared__ float redS[8 * 128];      // 4 KB; reused as ppRH in epilogue
  __shared__ float redQ[8 * 128];      // 4 KB; reused as ppH
  __shared__ float mu_s[128], rs_s[128];

  const int tid    = threadIdx.x;
  const int lane   = tid & 63;
  const int wid    = tid >> 6;        // 0..15
  const int rowgrp = wid >> 3;        // 0..1
  const int colgrp = wid & 7;         // 0..7
  const int llo    = lane & 15;
  const int lhi    = lane >> 4;
  const int wcol   = colgrp * 64;
  const int rbase  = rowgrp * 64;
  const int r0     = blockIdx.x * BM;

  // staging mapping: thread -> row tid>>3 (0..127), 4 floats at slot tid&7
  const int arow = tid >> 3;
  const int ac8  = (tid & 7) * 8;           // byte offset of 4 bf16 within slice row
  const float* aslice = hiddens + (size_t)(r0 + arow) * HDIM + (tid & 7) * 4;
  char* asb = (char*)As + arow * 1024;
  const int sw = (arow & 7) << 4;

  f32x4 acc[4][4];
  #pragma unroll
  for (int i = 0; i < 4; i++)
    #pragma unroll
    for (int j = 0; j < 4; j++)
      #pragma unroll
      for (int k = 0; k < 4; k++) acc[i][j][k] = 0.f;

  // ---- prologue: prefetch A slices 0,1; B fragments slice 0; write A slice 0
  float4 pref0 = *(const float4*)(aslice);
  float4 pref1 = *(const float4*)(aslice + 32);
  const bf16x8* wp = (const bf16x8*)wpack + ((size_t)colgrp * 16 * 4) * 64 + lane;
  bf16x8 bfr[4];
  #pragma unroll
  for (int ni = 0; ni < 4; ni++) bfr[ni] = wp[ni * 64];
  {
    uint2 w; w.x = pack_trunc(pref0.x, pref0.y); w.y = pack_trunc(pref0.z, pref0.w);
    *(uint2*)(asb + (ac8 ^ sw)) = w;
  }
  asm volatile("s_waitcnt lgkmcnt(0)" ::: "memory");
  __builtin_amdgcn_s_barrier();

  // ---- pipelined K loop: 16 slices of K=32
  #pragma unroll 2
  for (int kb = 0; kb < 16; kb++){
    // A frags for slice kb from LDS (wave's 64 rows)
    bf16x8 af[4];
    #pragma unroll
    for (int mi = 0; mi < 4; mi++){
      int row = rbase + mi * 16 + llo;
      af[mi] = *(const bf16x8*)((char*)As + row * 1024
                 + ((kb * 64 + lhi * 16) ^ ((row & 7) << 4)));
    }
    // register prefetch of A slice kb+2
    if ((kb & 1) == 0){ if (kb + 2 < 16) pref0 = *(const float4*)(aslice + (kb + 2) * 32); }
    else              { if (kb + 2 < 16) pref1 = *(const float4*)(aslice + (kb + 2) * 32); }
    // MFMAs consume bfr (loaded one slice ago)
    #pragma unroll
    for (int mi = 0; mi < 4; mi++)
      #pragma unroll
      for (int ni = 0; ni < 4; ni++)
        acc[mi][ni] = __builtin_amdgcn_mfma_f32_16x16x32_bf16(af[mi], bfr[ni], acc[mi][ni], 0, 0, 0);
    // B prefetch for slice kb+1 (after last bfr use; in flight across barrier)
    if (kb + 1 < 16){
      const bf16x8* wpn = wp + (kb + 1) * 4 * 64;
      #pragma unroll
      for (int ni = 0; ni < 4; ni++) bfr[ni] = wpn[ni * 64];
    }
    // stage A slice kb+1 (data prefetched last iter)
    if (kb + 1 < 16){
      float4 p = ((kb + 1) & 1) ? pref1 : pref0;
      uint2 w; w.x = pack_trunc(p.x, p.y); w.y = pack_trunc(p.z, p.w);
      *(uint2*)(asb + (((kb + 1) * 64 + ac8) ^ sw)) = w;
    }
    asm volatile("s_waitcnt lgkmcnt(0)" ::: "memory");
    __builtin_amdgcn_s_barrier();
  }

  // ---- add xWri, per-row LN stats (sum over 8 colgrps via LDS)
  float xw[4], g4[4], b4[4];
  #pragma unroll
  for (int ni = 0; ni < 4; ni++){
    int c = wcol + ni * 16 + llo;
    xw[ni] = xWri[c];
    g4[ni] = gr[c];
    b4[ni] = br[c];
  }
  #pragma unroll
  for (int mi = 0; mi < 4; mi++){
    #pragma unroll
    for (int rr = 0; rr < 4; rr++){
      float sv = 0.f, qv = 0.f;
      #pragma unroll
      for (int ni = 0; ni < 4; ni++){
        float v = acc[mi][ni][rr] + xw[ni];
        acc[mi][ni][rr] = v;
        sv += v; qv += v * v;
      }
      #pragma unroll
      for (int m = 1; m < 16; m <<= 1){
        sv += __shfl_xor(sv, m, 64);
        qv += __shfl_xor(qv, m, 64);
      }
      if (llo == 0){
        int row = rbase + mi * 16 + lhi * 4 + rr;   // 0..127
        redS[colgrp * 128 + row] = sv;
        redQ[colgrp * 128 + row] = qv;
      }
    }
  }
  __syncthreads();
  if (tid < 128){
    float S = 0.f, Q = 0.f;
    #pragma unroll
    for (int w = 0; w < 8; w++){ S += redS[w * 128 + tid]; Q += redQ[w * 128 + tid]; }
    float mu  = S * (1.f / 512.f);
    float var = Q * (1.f / 512.f) - mu * mu;
    mu_s[tid] = mu;
    rs_s[tid] = rsqrtf(var + 1e-5f);
  }
  __syncthreads();

  // ---- r = sigmoid(LN(v)); psums from h (bf16) in As; reduce over lhi
  float prh[4] = {0.f, 0.f, 0.f, 0.f};
  float ph [4] = {0.f, 0.f, 0.f, 0.f};
  #pragma unroll
  for (int mi = 0; mi < 4; mi++){
    #pragma unroll
    for (int rr = 0; rr < 4; rr++){
      int row = rbase + mi * 16 + lhi * 4 + rr;
      float mu = mu_s[row], rs = rs_s[row];
      int sw2 = (row & 7) << 4;
      #pragma unroll
      for (int ni = 0; ni < 4; ni++){
        float v = (acc[mi][ni][rr] - mu) * rs * g4[ni] + b4[ni];
        float r = __builtin_amdgcn_rcpf(1.f + __expf(-v));
        int col = wcol + ni * 16 + llo;
        float h = bf2f(*(const unsigned short*)((char*)As + row * 1024 + ((col * 2) ^ sw2)));
        prh[ni] += r * h;
        ph [ni] += h;
      }
    }
  }
  #pragma unroll
  for (int ni = 0; ni < 4; ni++){
    prh[ni] += __shfl_xor(prh[ni], 16, 64);
    prh[ni] += __shfl_xor(prh[ni], 32, 64);
    ph [ni] += __shfl_xor(ph [ni], 16, 64);
    ph [ni] += __shfl_xor(ph [ni], 32, 64);
  }
  // cross-rowgroup combine via reused redS/redQ (stats phase done)
  float* ppRH = redS;   // [2][512]
  float* ppH  = redQ;   // [2][512]
  if (lhi == 0){
    #pragma unroll
    for (int ni = 0; ni < 4; ni++){
      int col = wcol + ni * 16 + llo;
      ppRH[rowgrp * 512 + col] = prh[ni];
      ppH [rowgrp * 512 + col] = ph[ni];
    }
  }
  __syncthreads();
  if (tid < 512){
    psum_rh[(size_t)blockIdx.x * HDIM + tid] = ppRH[tid] + ppRH[512 + tid];
    psum_h [(size_t)blockIdx.x * HDIM + tid] = ppH[tid]  + ppH[512 + tid];
  }
}

// ---------------- kernel 3: reduce partials, build cat vectors ---------------
__global__ __launch_bounds__(256) void reduce_psums(
    const float* __restrict__ psum_rh, const float* __restrict__ psum_h,
    const float* __restrict__ x, float* __restrict__ catz, float* __restrict__ catu,
    int nblk)
{
  __shared__ float L[8][32];
  int b = blockIdx.x, t = threadIdx.x;
  if (b < 32){
    const float* P = (b < 16) ? psum_rh : psum_h;
    int c0 = (b & 15) * 32;
    int wj = t >> 5, ci = t & 31;
    float a = 0.f;
    for (int s = wj; s < nblk; s += 8) a += P[(size_t)s * 512 + c0 + ci];
    L[wj][ci] = a;
    __syncthreads();
    if (t < 32){
      float r = 0.f;
      #pragma unroll
      for (int w = 0; w < 8; w++) r += L[w][t];
      if (b < 16) catu[512 + c0 + t] = r;   // (r*hiddens).sum(0)
      else        catz[512 + c0 + t] = r;   // hidden_sum
    }
  } else {
    int i = ((b - 32) & 1) * 256 + t;       // 0..511
    if (b < 34) catz[i] = x[i];
    else        catu[i] = x[i];
  }
}

// ---------------- kernel 4: zpre = Wz@catz, upre = Wu@catu (one launch) ------
__global__ __launch_bounds__(256) void matvec_zu(
    const float* __restrict__ Wz, const float* __restrict__ Wu,
    const float* __restrict__ catz, const float* __restrict__ catu,
    float* __restrict__ zpre, float* __restrict__ upre)
{
  int b = blockIdx.x, lane = threadIdx.x & 63, wid = threadIdx.x >> 6;
  int row = (b & 127) * 4 + wid;
  const float* W = (b < 128) ? Wz : Wu;
  const float* v = (b < 128) ? catz : catu;
  float*       o = (b < 128) ? zpre : upre;
  const float* Wr = W + (size_t)row * 1024;
  float a = 0.f;
  #pragma unroll
  for (int k = 0; k < 1024 / 64; k++) a += v[k*64 + lane] * Wr[k*64 + lane];
  #pragma unroll
  for (int m = 1; m < 64; m <<= 1) a += __shfl_xor(a, m, 64);
  if (lane == 0) o[row] = a;
}

// ---------------- kernel 5: final LN + gates + output ------------------------
__global__ __launch_bounds__(512) void finalize_k(
    const float* __restrict__ zpre, const float* __restrict__ upre,
    const float* __restrict__ gz, const float* __restrict__ bz,
    const float* __restrict__ gu, const float* __restrict__ bu,
    const float* __restrict__ catz, float* __restrict__ out)
{
  __shared__ float R[8][4];
  int t = threadIdx.x, lane = t & 63, wid = t >> 6;
  float zp = zpre[t], up = upre[t];
  float zs = zp, zq = zp * zp, us = up, uq = up * up;
  #pragma unroll
  for (int m = 1; m < 64; m <<= 1){
    zs += __shfl_xor(zs, m, 64); zq += __shfl_xor(zq, m, 64);
    us += __shfl_xor(us, m, 64); uq += __shfl_xor(uq, m, 64);
  }
  if (lane == 0){ R[wid][0] = zs; R[wid][1] = zq; R[wid][2] = us; R[wid][3] = uq; }
  __syncthreads();
  float ZS = 0.f, ZQ = 0.f, US = 0.f, UQ = 0.f;
  #pragma unroll
  for (int w = 0; w < 8; w++){ ZS += R[w][0]; ZQ += R[w][1]; US += R[w][2]; UQ += R[w][3]; }
  float zmu = ZS / 512.f, zrs = rsqrtf(ZQ / 512.f - zmu * zmu + 1e-5f);
  float umu = US / 512.f, urs = rsqrtf(UQ / 512.f - umu * umu + 1e-5f);
  float z = 1.f / (1.f + expf(-((zp - zmu) * zrs * gz[t] + bz[t])));
  float u = tanhf((up - umu) * urs * gu[t] + bu[t]);
  float hs = catz[512 + t];
  out[t] = z * hs + (1.f - z) * u;
}

// -----------------------------------------------------------------------------
extern "C" void kernel_launch(void* const* d_in, const int* in_sizes, int n_in,
                              void* d_out, int out_size, void* d_ws, size_t ws_size,
                              hipStream_t stream)
{
  const float* x   = (const float*)d_in[0];
  const float* hid = (const float*)d_in[1];
  const float* Wz  = (const float*)d_in[2];
  const float* Wri = (const float*)d_in[3];
  const float* Wrh = (const float*)d_in[4];
  const float* Wu  = (const float*)d_in[5];
  const float* gz  = (const float*)d_in[6];
  const float* bz  = (const float*)d_in[7];
  const float* gr  = (const float*)d_in[8];
  const float* br  = (const float*)d_in[9];
  const float* gu  = (const float*)d_in[10];
  const float* bu  = (const float*)d_in[11];
  (void)n_in; (void)out_size; (void)ws_size;

  const int M    = in_sizes[1] / HDIM;   // 65536
  const int nblk = M / BM;               // 512

  char* ws = (char*)d_ws;
  unsigned short* wpack = (unsigned short*)ws;              // 512 KB
  float* xwri    = (float*)(ws + 524288);                   // 2 KB
  float* psum_rh = (float*)(ws + 526336);                   // nblk*512*4
  float* psum_h  = (float*)(ws + 526336 + (size_t)nblk * 2048);
  char*  p2      = ws + 526336 + (size_t)nblk * 4096;
  float* catz    = (float*)p2;                              // 4 KB
  float* catu    = (float*)(p2 + 4096);                     // 4 KB
  float* zpre    = (float*)(p2 + 8192);                     // 2 KB
  float* upre    = (float*)(p2 + 10240);                    // 2 KB
  float* out     = (float*)d_out;

  hipLaunchKernelGGL(prep_k,       dim3(256),  dim3(256),  0, stream, Wrh, wpack, Wri, x, xwri);
  hipLaunchKernelGGL(fused_r,      dim3(nblk), dim3(1024), 0, stream, hid, wpack, xwri, gr, br, psum_rh, psum_h);
  hipLaunchKernelGGL(reduce_psums, dim3(36),   dim3(256),  0, stream, psum_rh, psum_h, x, catz, catu, nblk);
  hipLaunchKernelGGL(matvec_zu,    dim3(256),  dim3(256),  0, stream, Wz, Wu, catz, catu, zpre, upre);
  hipLaunchKernelGGL(finalize_k,   dim3(1),    dim3(512),  0, stream, zpre, upre, gz, bz, gu, bu, catz, out);
}